// Round 3
// baseline (4037.957 us; speedup 1.0000x reference)
//
#include <hip/hip_runtime.h>

#define C  64
#define KK 27
#define BB 4

// ===================== fast-path ws layout (float offsets) =====================
//      0 : pooled[256]
//    256 : counts[4]
//    260 : gate[256]
//    516 : bnscale[64]
//    580 : bnshift[64]
//    644 : kcnt[27]   (int)
//    671 : kbase[27]  (int)
//    698 : cursor[27] (int)
//    725 : nseg[1]    (int)
//   1024 : seg2k[12288] (int)
//  16384 : pairs[2*PAIR_CAP] (int)  (src,dst interleaved)
//  16384+2*PAIR_CAP : h[N*C]
#define PAIR_CAP 1250000
#define SEGMAX   12288

__global__ __launch_bounds__(256) void init_ws(float* ws) {
  int t = blockIdx.x * 256 + threadIdx.x;
  if (t < 1024) ws[t] = 0.f;
}

__global__ __launch_bounds__(256) void zero_h(float4* __restrict__ p, long n4) {
  long i = (long)blockIdx.x * 256 + threadIdx.x;
  long stride = (long)gridDim.x * 256;
  float4 z = make_float4(0.f, 0.f, 0.f, 0.f);
  for (; i < n4; i += stride) p[i] = z;
}

__global__ __launch_bounds__(256) void pool_kernel(
    const float* __restrict__ x, const int* __restrict__ bidx,
    float* __restrict__ pooled, float* __restrict__ counts, int N)
{
  const int PTS = 4096;
  int base = blockIdx.x * PTS;
  int col = threadIdx.x & 63;
  int row = threadIdx.x >> 6;            // 0..3
  float a0 = 0.f, a1 = 0.f, a2 = 0.f, a3 = 0.f;
  int   c0 = 0, c1 = 0, c2 = 0, c3 = 0;
  for (int i = row; i < PTS; i += 4) {
    int n = base + i;
    if (n >= N) break;
    int b = bidx[n];
    float v = x[((size_t)n << 6) + col];
    if (b == 0)      { a0 += v; c0++; }
    else if (b == 1) { a1 += v; c1++; }
    else if (b == 2) { a2 += v; c2++; }
    else             { a3 += v; c3++; }
  }
  __shared__ float red[BB][4][C];
  __shared__ int   cred[BB][4];
  red[0][row][col] = a0; red[1][row][col] = a1;
  red[2][row][col] = a2; red[3][row][col] = a3;
  if (col == 0) { cred[0][row] = c0; cred[1][row] = c1; cred[2][row] = c2; cred[3][row] = c3; }
  __syncthreads();
  {
    int b = threadIdx.x >> 6, c = threadIdx.x & 63;
    float s = red[b][0][c] + red[b][1][c] + red[b][2][c] + red[b][3][c];
    if (s != 0.f) atomicAdd(&pooled[b * C + c], s);
  }
  if (threadIdx.x < BB) {
    int b = threadIdx.x;
    int s = cred[b][0] + cred[b][1] + cred[b][2] + cred[b][3];
    if (s) atomicAdd(&counts[b], (float)s);
  }
}

__global__ __launch_bounds__(256) void gate_kernel(
    const float* __restrict__ pooled, const float* __restrict__ counts,
    const float* __restrict__ w_fc1, const float* __restrict__ b_fc1,
    const float* __restrict__ w_fc2, const float* __restrict__ b_fc2,
    const float* __restrict__ bn_gamma, const float* __restrict__ bn_beta,
    const float* __restrict__ bn_mean, const float* __restrict__ bn_var,
    float* __restrict__ gate, float* __restrict__ bnscale, float* __restrict__ bnshift)
{
  __shared__ float mean[BB * C];
  __shared__ float hh[BB * 16];
  int t = threadIdx.x;
  { int b = t >> 6; mean[t] = pooled[t] / counts[b]; }
  __syncthreads();
  if (t < BB * 16) {
    int b = t >> 4, r = t & 15;
    float s = b_fc1[r];
    for (int c = 0; c < C; ++c) s += mean[b * C + c] * w_fc1[c * 16 + r];
    hh[t] = fmaxf(s, 0.f);
  }
  __syncthreads();
  {
    int b = t >> 6, c = t & 63;
    float s = b_fc2[c];
    for (int r = 0; r < 16; ++r) s += hh[b * 16 + r] * w_fc2[r * 64 + c];
    gate[t] = 1.f / (1.f + expf(-s));
  }
  if (t < C) {
    float sc = bn_gamma[t] * rsqrtf(bn_var[t] + 1e-5f);
    bnscale[t] = sc;
    bnshift[t] = bn_beta[t] - bn_mean[t] * sc;
  }
}

// ---------------- pair-list build ----------------
__global__ __launch_bounds__(256) void count_pairs(
    const int* __restrict__ nbr, int* __restrict__ kcnt, int N)
{
  __shared__ int h[KK];
  int t = threadIdx.x;
  if (t < KK) h[t] = 0;
  __syncthreads();
  int n = blockIdx.x * 256 + t;
  if (n < N) {
#pragma unroll
    for (int k = 0; k < KK; ++k) {
      if (k == 13) continue;
      if (nbr[(size_t)k * N + n] >= 0) atomicAdd(&h[k], 1);
    }
  }
  __syncthreads();
  if (t < KK && h[t]) atomicAdd(&kcnt[t], h[t]);
}

__global__ void scan_pairs(int* __restrict__ kcnt, int* __restrict__ kbase,
                           int* __restrict__ cursor, int* __restrict__ nseg, int cap)
{
  if (threadIdx.x == 0) {
    int off = 0;
    for (int k = 0; k < KK; ++k) {
      kbase[k] = off;
      int c = (k == 13) ? 0 : kcnt[k];
      int pad = (c + 127) & ~127;
      if (off + pad > cap) { kcnt[k] = 0; pad = 0; }   // safety clamp (never expected)
      off += pad;
    }
    int s = off >> 7;
    nseg[0] = (s > SEGMAX) ? SEGMAX : s;
  }
  if (threadIdx.x < KK) cursor[threadIdx.x] = 0;
}

__global__ __launch_bounds__(256) void fill_seg2k(
    const int* __restrict__ kbase, const int* __restrict__ nseg, int* __restrict__ seg2k)
{
  int j = blockIdx.x * 256 + threadIdx.x;
  if (j >= nseg[0]) return;
  int p = j << 7;
  int k = KK - 1;
#pragma unroll
  for (int q = 1; q < KK; ++q) { if (p < kbase[q]) { k = q - 1; break; } }
  seg2k[j] = k;
}

__global__ __launch_bounds__(256) void fill_pairs(
    const int* __restrict__ nbr, const int* __restrict__ kbase, const int* __restrict__ kcnt,
    int* __restrict__ cursor, int* __restrict__ pairs, int N)
{
  __shared__ int h[KK], base[KK], h2[KK];
  int t = threadIdx.x;
  if (t < KK) { h[t] = 0; h2[t] = 0; }
  __syncthreads();
  int n = blockIdx.x * 256 + t;
  int v[KK];
  if (n < N) {
#pragma unroll
    for (int k = 0; k < KK; ++k) {
      v[k] = (k == 13) ? -1 : nbr[(size_t)k * N + n];
      if (k != 13 && v[k] >= 0) atomicAdd(&h[k], 1);
    }
  }
  __syncthreads();
  if (t < KK && h[t]) base[t] = atomicAdd(&cursor[t], h[t]);
  __syncthreads();
  if (n < N) {
#pragma unroll
    for (int k = 0; k < KK; ++k) {
      if (k == 13 || v[k] < 0) continue;
      int pos = base[k] + atomicAdd(&h2[k], 1);
      if (pos < kcnt[k]) {
        int slot = kbase[k] + pos;
        pairs[slot * 2]     = v[k];   // src
        pairs[slot * 2 + 1] = n;      // dst
      }
    }
  }
}

// ---------------- GEMM microkernel: 128 rows x 64 cols from LDS ----------------
// Al stride 68 floats (row pad: adjacent rows 4 banks apart -> conflict-free b128)
__device__ __forceinline__ void gemm_micro(const float* Al, const float* Wl,
                                           int rowBase, int coBase, float acc[4][8])
{
#pragma unroll
  for (int i = 0; i < 4; ++i)
#pragma unroll
    for (int j = 0; j < 8; ++j) acc[i][j] = 0.f;
#pragma unroll 4
  for (int ci = 0; ci < 64; ci += 4) {
    float av[4][4];
    *(float4*)av[0] = *(const float4*)&Al[(rowBase     ) * 68 + ci];
    *(float4*)av[1] = *(const float4*)&Al[(rowBase +  8) * 68 + ci];
    *(float4*)av[2] = *(const float4*)&Al[(rowBase + 16) * 68 + ci];
    *(float4*)av[3] = *(const float4*)&Al[(rowBase + 24) * 68 + ci];
#pragma unroll
    for (int q = 0; q < 4; ++q) {
      float w8[8];
      *(float4*)&w8[0] = *(const float4*)&Wl[(ci + q) * 64 + coBase];
      *(float4*)&w8[4] = *(const float4*)&Wl[(ci + q) * 64 + coBase + 4];
#pragma unroll
      for (int i = 0; i < 4; ++i)
#pragma unroll
        for (int j = 0; j < 8; ++j)
          acc[i][j] = fmaf(av[i][q], w8[j], acc[i][j]);
    }
  }
}

// ---------------- per-k gather-GEMM-scatter ----------------
template <int GATE>
__global__ __launch_bounds__(256) void scatter_k(
    const float* __restrict__ x, const float* __restrict__ Wfull,
    const int* __restrict__ pairs, const int* __restrict__ kcnt,
    const int* __restrict__ kbase, const int* __restrict__ seg2k,
    const int* __restrict__ nseg_p, const float* __restrict__ gate,
    const int* __restrict__ bidx, float* __restrict__ out)
{
  __shared__ float Wl[4096];
  __shared__ float Al[128 * 68];
  __shared__ int Sl[128], Dl[128];
  if ((int)blockIdx.x >= nseg_p[0]) return;
  int t = threadIdx.x;
  int k = seg2k[blockIdx.x];
  int pBase = blockIdx.x << 7;
  int pCnt = min(128, kcnt[k] - (pBase - kbase[k]));
  const float* Ws = Wfull + ((size_t)k << 12);
  for (int i = t; i < 4096; i += 256) Wl[i] = Ws[i];
  if (t < 128) {
    int s = -1, d = -1;
    if (t < pCnt) { s = pairs[(pBase + t) << 1]; d = pairs[((pBase + t) << 1) | 1]; }
    Sl[t] = s; Dl[t] = d;
  }
  __syncthreads();
  int rr = t >> 4, c4 = (t & 15) << 2;
  for (int it = 0; it < 8; ++it) {
    int r = (it << 4) + rr;
    float4 v = make_float4(0.f, 0.f, 0.f, 0.f);
    int src = Sl[r];
    if (src >= 0) {
      v = *(const float4*)(x + ((size_t)src << 6) + c4);
      if (GATE) {
        const float* g = gate + (bidx[src] << 6) + c4;
        v.x *= g[0]; v.y *= g[1]; v.z *= g[2]; v.w *= g[3];
      }
    }
    *(float4*)&Al[r * 68 + c4] = v;
  }
  __syncthreads();
  int wv = t >> 6, lane = t & 63, pg = lane >> 3, cg = lane & 7;
  int rowBase = (wv << 5) + pg, coBase = cg << 3;
  float acc[4][8];
  gemm_micro(Al, Wl, rowBase, coBase, acc);
#pragma unroll
  for (int i = 0; i < 4; ++i) {
    int r = rowBase + (i << 3);
    int d = Dl[r];
    if (d >= 0) {
      float* o = out + ((size_t)d << 6) + coBase;
#pragma unroll
      for (int j = 0; j < 8; ++j) unsafeAtomicAdd(&o[j], acc[i][j]);
    }
  }
}

// ---------------- dense center GEMM + fused epilogue ----------------
// MODE 0: conv1 (gated A, read hraw partial, BN+ReLU, write h in place)
// MODE 1: conv2 (A = h, +bias epilogue, write out; scatter adds afterwards)
template <int MODE>
__global__ __launch_bounds__(256) void center_epi(
    const float* __restrict__ x, const float* __restrict__ Wfull,
    const float* __restrict__ gate, const int* __restrict__ bidx,
    const float* __restrict__ ep_a, const float* __restrict__ ep_b,
    const float* hraw, float* __restrict__ out, int N)
{
  __shared__ float Wl[4096];
  __shared__ float Al[128 * 68];
  int t = threadIdx.x;
  int n0 = blockIdx.x << 7;
  int pCnt = min(128, N - n0);
  const float* Ws = Wfull + ((size_t)13 << 12);
  for (int i = t; i < 4096; i += 256) Wl[i] = Ws[i];
  int rr = t >> 4, c4 = (t & 15) << 2;
  for (int it = 0; it < 8; ++it) {
    int r = (it << 4) + rr;
    float4 v = make_float4(0.f, 0.f, 0.f, 0.f);
    if (r < pCnt) {
      int n = n0 + r;
      v = *(const float4*)(x + ((size_t)n << 6) + c4);
      if (MODE == 0) {
        const float* g = gate + (bidx[n] << 6) + c4;
        v.x *= g[0]; v.y *= g[1]; v.z *= g[2]; v.w *= g[3];
      }
    }
    *(float4*)&Al[r * 68 + c4] = v;
  }
  __syncthreads();
  int wv = t >> 6, lane = t & 63, pg = lane >> 3, cg = lane & 7;
  int rowBase = (wv << 5) + pg, coBase = cg << 3;
  float acc[4][8];
  gemm_micro(Al, Wl, rowBase, coBase, acc);
#pragma unroll
  for (int i = 0; i < 4; ++i) {
    int r = rowBase + (i << 3);
    if (r < pCnt) {
      size_t o = (((size_t)(n0 + r)) << 6) + coBase;
      if (MODE == 0) {
#pragma unroll
        for (int j = 0; j < 8; ++j) {
          float tot = acc[i][j] + hraw[o + j];
          out[o + j] = fmaxf(fmaf(tot, ep_a[coBase + j], ep_b[coBase + j]), 0.f);
        }
      } else {
#pragma unroll
        for (int j = 0; j < 8; ++j) out[o + j] = acc[i][j] + ep_b[coBase + j];
      }
    }
  }
}

// ---------------- round-1 fallback (small ws) ----------------
__global__ __launch_bounds__(256) void scale_w1(
    const float* __restrict__ w1, const float* __restrict__ gate,
    float* __restrict__ w1g)
{
  int b = blockIdx.x & 3, k = blockIdx.x >> 2;
  const float* src = w1 + ((size_t)k << 12);
  float* dst = w1g + (((size_t)(b * KK + k)) << 12);
  const float* g = gate + (b << 6);
  for (int it = 0; it < 16; ++it) {
    int pos = it * 256 + threadIdx.x;
    int ci = pos >> 6;
    dst[pos] = g[ci] * src[pos];
  }
}

template <int MODE>
__global__ __launch_bounds__(256) void spconv_kernel(
    const float* __restrict__ x, const int* __restrict__ nbr,
    const int* __restrict__ bidx, const float* __restrict__ W,
    const float* __restrict__ ep_a, const float* __restrict__ ep_b,
    float* __restrict__ out, int N)
{
  int wid = (int)((blockIdx.x * 256u + threadIdx.x) >> 6);
  if (wid >= N) return;
  int lane = threadIdx.x & 63;
  int n = __builtin_amdgcn_readfirstlane(wid);
  const float* Wb = W;
  if (MODE == 0) {
    int b = __builtin_amdgcn_readfirstlane(bidx[n]);
    Wb += (size_t)b * (KK * C * C);
  }
  float acc = 0.f;
#pragma unroll 1
  for (int k = 0; k < KK; ++k) {
    int idx = __builtin_amdgcn_readfirstlane(nbr[(size_t)k * N + n]);
    if (idx < 0) continue;
    const float* xr = x + ((size_t)idx << 6);
    const float* wr = Wb + (k << 12) + lane;
#pragma unroll
    for (int ci = 0; ci < C; ++ci) acc = fmaf(xr[ci], wr[ci << 6], acc);
  }
  float r;
  if (MODE == 0) r = fmaxf(fmaf(acc, ep_a[lane], ep_b[lane]), 0.f);
  else           r = acc + ep_b[lane];
  out[((size_t)n << 6) + lane] = r;
}

extern "C" void kernel_launch(void* const* d_in, const int* in_sizes, int n_in,
                              void* d_out, int out_size, void* d_ws, size_t ws_size,
                              hipStream_t stream) {
  const float* feats   = (const float*)d_in[0];
  const int*   nbr     = (const int*)  d_in[1];
  const int*   bidx    = (const int*)  d_in[2];
  const float* w_fc1   = (const float*)d_in[3];
  const float* b_fc1   = (const float*)d_in[4];
  const float* w_fc2   = (const float*)d_in[5];
  const float* b_fc2   = (const float*)d_in[6];
  const float* w_conv1 = (const float*)d_in[7];
  const float* bn_gamma= (const float*)d_in[8];
  const float* bn_beta = (const float*)d_in[9];
  const float* bn_mean = (const float*)d_in[10];
  const float* bn_var  = (const float*)d_in[11];
  const float* w_conv2 = (const float*)d_in[12];
  const float* b_conv2 = (const float*)d_in[13];

  int N = in_sizes[0] / C;
  float* ws      = (float*)d_ws;
  float* pooled  = ws;
  float* counts  = ws + 256;
  float* gate    = ws + 260;
  float* bnscale = ws + 516;
  float* bnshift = ws + 580;
  float* out     = (float*)d_out;

  size_t need = ((size_t)16384 + 2ull * PAIR_CAP + (size_t)N * C) * 4ull;

  if (ws_size >= need) {
    int* kcnt   = (int*)(ws + 644);
    int* kbase  = (int*)(ws + 671);
    int* cursor = (int*)(ws + 698);
    int* nseg   = (int*)(ws + 725);
    int* seg2k  = (int*)(ws + 1024);
    int* pairs  = (int*)(ws + 16384);
    float* h    = ws + 16384 + 2ull * PAIR_CAP;

    hipLaunchKernelGGL(init_ws, dim3(4), dim3(256), 0, stream, ws);
    hipLaunchKernelGGL(pool_kernel, dim3((N + 4095) / 4096), dim3(256), 0, stream,
                       feats, bidx, pooled, counts, N);
    hipLaunchKernelGGL(gate_kernel, dim3(1), dim3(256), 0, stream,
                       pooled, counts, w_fc1, b_fc1, w_fc2, b_fc2,
                       bn_gamma, bn_beta, bn_mean, bn_var, gate, bnscale, bnshift);
    hipLaunchKernelGGL(count_pairs, dim3((N + 255) / 256), dim3(256), 0, stream,
                       nbr, kcnt, N);
    hipLaunchKernelGGL(scan_pairs, dim3(1), dim3(32), 0, stream,
                       kcnt, kbase, cursor, nseg, (int)PAIR_CAP);
    hipLaunchKernelGGL(fill_seg2k, dim3(SEGMAX / 256), dim3(256), 0, stream,
                       kbase, nseg, seg2k);
    hipLaunchKernelGGL(fill_pairs, dim3((N + 255) / 256), dim3(256), 0, stream,
                       nbr, kbase, kcnt, cursor, pairs, N);
    hipLaunchKernelGGL(zero_h, dim3(2048), dim3(256), 0, stream,
                       (float4*)h, (long)N * (C / 4));
    // conv1: scatter non-center into h, then fused center + BN + ReLU (in place)
    hipLaunchKernelGGL((scatter_k<1>), dim3(SEGMAX), dim3(256), 0, stream,
                       feats, w_conv1, pairs, kcnt, kbase, seg2k, nseg, gate, bidx, h);
    hipLaunchKernelGGL((center_epi<0>), dim3((N + 127) / 128), dim3(256), 0, stream,
                       feats, w_conv1, gate, bidx, bnscale, bnshift, h, h, N);
    // conv2: center + bias writes out, then scatter non-center on top
    hipLaunchKernelGGL((center_epi<1>), dim3((N + 127) / 128), dim3(256), 0, stream,
                       h, w_conv2, nullptr, nullptr, nullptr, b_conv2, nullptr, out, N);
    hipLaunchKernelGGL((scatter_k<0>), dim3(SEGMAX), dim3(256), 0, stream,
                       h, w_conv2, pairs, kcnt, kbase, seg2k, nseg, nullptr, nullptr, out);
  } else {
    // round-1 fallback path
    float* w1g = ws + 1024;
    float* h   = ws + 1024 + BB * KK * C * C;
    hipLaunchKernelGGL(init_ws, dim3(4), dim3(256), 0, stream, ws);
    hipLaunchKernelGGL(pool_kernel, dim3((N + 4095) / 4096), dim3(256), 0, stream,
                       feats, bidx, pooled, counts, N);
    hipLaunchKernelGGL(gate_kernel, dim3(1), dim3(256), 0, stream,
                       pooled, counts, w_fc1, b_fc1, w_fc2, b_fc2,
                       bn_gamma, bn_beta, bn_mean, bn_var, gate, bnscale, bnshift);
    hipLaunchKernelGGL(scale_w1, dim3(KK * BB), dim3(256), 0, stream,
                       w_conv1, gate, w1g);
    hipLaunchKernelGGL((spconv_kernel<0>), dim3((N + 3) / 4), dim3(256), 0, stream,
                       feats, nbr, bidx, w1g, bnscale, bnshift, h, N);
    hipLaunchKernelGGL((spconv_kernel<1>), dim3((N + 3) / 4), dim3(256), 0, stream,
                       h, nbr, bidx, w_conv2, nullptr, b_conv2, out, N);
  }
}

// Round 4
// 1720.826 us; speedup vs baseline: 2.3465x; 2.3465x over previous
//
#include <hip/hip_runtime.h>

#define C  64
#define KK 27
#define BB 4

// ===================== fast-path ws layout (float offsets) =====================
//      0 : pooled[256]
//    256 : counts[4]
//    260 : gate[256]
//    516 : bnscale[64]
//    580 : bnshift[64]
//    644 : kcnt[27]   (int)
//    671 : kbase[27]  (int)
//    698 : cursor[27] (int)
//    725 : nseg[1]    (int)
//   1024 : seg2k[12288] (int)
//  16384 : pairs[2*PAIR_CAP] (int)  (src,dst interleaved)
//  16384+2*PAIR_CAP : h[N*C]
#define PAIR_CAP 1250000
#define SEGMAX   12288

__global__ __launch_bounds__(256) void init_ws(float* ws) {
  int t = blockIdx.x * 256 + threadIdx.x;
  if (t < 1024) ws[t] = 0.f;
}

__global__ __launch_bounds__(256) void zero_h(float4* __restrict__ p, long n4) {
  long i = (long)blockIdx.x * 256 + threadIdx.x;
  long stride = (long)gridDim.x * 256;
  float4 z = make_float4(0.f, 0.f, 0.f, 0.f);
  for (; i < n4; i += stride) p[i] = z;
}

__global__ __launch_bounds__(256) void pool_kernel(
    const float* __restrict__ x, const int* __restrict__ bidx,
    float* __restrict__ pooled, float* __restrict__ counts, int N)
{
  const int PTS = 4096;
  int base = blockIdx.x * PTS;
  int col = threadIdx.x & 63;
  int row = threadIdx.x >> 6;            // 0..3
  float a0 = 0.f, a1 = 0.f, a2 = 0.f, a3 = 0.f;
  int   c0 = 0, c1 = 0, c2 = 0, c3 = 0;
  for (int i = row; i < PTS; i += 4) {
    int n = base + i;
    if (n >= N) break;
    int b = bidx[n];
    float v = x[((size_t)n << 6) + col];
    if (b == 0)      { a0 += v; c0++; }
    else if (b == 1) { a1 += v; c1++; }
    else if (b == 2) { a2 += v; c2++; }
    else             { a3 += v; c3++; }
  }
  __shared__ float red[BB][4][C];
  __shared__ int   cred[BB][4];
  red[0][row][col] = a0; red[1][row][col] = a1;
  red[2][row][col] = a2; red[3][row][col] = a3;
  if (col == 0) { cred[0][row] = c0; cred[1][row] = c1; cred[2][row] = c2; cred[3][row] = c3; }
  __syncthreads();
  {
    int b = threadIdx.x >> 6, c = threadIdx.x & 63;
    float s = red[b][0][c] + red[b][1][c] + red[b][2][c] + red[b][3][c];
    if (s != 0.f) atomicAdd(&pooled[b * C + c], s);
  }
  if (threadIdx.x < BB) {
    int b = threadIdx.x;
    int s = cred[b][0] + cred[b][1] + cred[b][2] + cred[b][3];
    if (s) atomicAdd(&counts[b], (float)s);
  }
}

__global__ __launch_bounds__(256) void gate_kernel(
    const float* __restrict__ pooled, const float* __restrict__ counts,
    const float* __restrict__ w_fc1, const float* __restrict__ b_fc1,
    const float* __restrict__ w_fc2, const float* __restrict__ b_fc2,
    const float* __restrict__ bn_gamma, const float* __restrict__ bn_beta,
    const float* __restrict__ bn_mean, const float* __restrict__ bn_var,
    float* __restrict__ gate, float* __restrict__ bnscale, float* __restrict__ bnshift)
{
  __shared__ float mean[BB * C];
  __shared__ float hh[BB * 16];
  int t = threadIdx.x;
  { int b = t >> 6; mean[t] = pooled[t] / counts[b]; }
  __syncthreads();
  if (t < BB * 16) {
    int b = t >> 4, r = t & 15;
    float s = b_fc1[r];
    for (int c = 0; c < C; ++c) s += mean[b * C + c] * w_fc1[c * 16 + r];
    hh[t] = fmaxf(s, 0.f);
  }
  __syncthreads();
  {
    int b = t >> 6, c = t & 63;
    float s = b_fc2[c];
    for (int r = 0; r < 16; ++r) s += hh[b * 16 + r] * w_fc2[r * 64 + c];
    gate[t] = 1.f / (1.f + expf(-s));
  }
  if (t < C) {
    float sc = bn_gamma[t] * rsqrtf(bn_var[t] + 1e-5f);
    bnscale[t] = sc;
    bnshift[t] = bn_beta[t] - bn_mean[t] * sc;
  }
}

// ---------------- pair-list build (ballot-based, no per-thread LDS atomics) ----------------
__global__ __launch_bounds__(256) void count_pairs(
    const int* __restrict__ nbr, int* __restrict__ kcnt, int N)
{
  __shared__ int wc[4][KK];
  int t = threadIdx.x, wv = t >> 6, lane = t & 63;
  int n = blockIdx.x * 256 + t;
  bool act = n < N;
#pragma unroll
  for (int k = 0; k < KK; ++k) {
    bool val = false;
    if (k != 13 && act) val = nbr[(size_t)k * N + n] >= 0;
    unsigned long long m = __ballot(val);
    if (lane == 0) wc[wv][k] = __popcll(m);
  }
  __syncthreads();
  if (t < KK) {
    int s = wc[0][t] + wc[1][t] + wc[2][t] + wc[3][t];
    if (s) atomicAdd(&kcnt[t], s);
  }
}

__global__ void scan_pairs(int* __restrict__ kcnt, int* __restrict__ kbase,
                           int* __restrict__ cursor, int* __restrict__ nseg, int cap)
{
  if (threadIdx.x == 0) {
    int off = 0;
    for (int k = 0; k < KK; ++k) {
      kbase[k] = off;
      int c = (k == 13) ? 0 : kcnt[k];
      int pad = (c + 127) & ~127;
      if (off + pad > cap) { kcnt[k] = 0; pad = 0; }   // safety clamp (never expected)
      off += pad;
    }
    int s = off >> 7;
    nseg[0] = (s > SEGMAX) ? SEGMAX : s;
  }
  if (threadIdx.x < KK) cursor[threadIdx.x] = 0;
}

__global__ __launch_bounds__(256) void fill_seg2k(
    const int* __restrict__ kbase, const int* __restrict__ nseg, int* __restrict__ seg2k)
{
  int j = blockIdx.x * 256 + threadIdx.x;
  if (j >= nseg[0]) return;
  int p = j << 7;
  int k = KK - 1;
#pragma unroll
  for (int q = 1; q < KK; ++q) { if (p < kbase[q]) { k = q - 1; break; } }
  seg2k[j] = k;
}

__global__ __launch_bounds__(256) void fill_pairs(
    const int* __restrict__ nbr, const int* __restrict__ kbase, const int* __restrict__ kcnt,
    int* __restrict__ cursor, int* __restrict__ pairs, int N)
{
  __shared__ int wc[4][KK];
  __shared__ int wb[4][KK];
  int t = threadIdx.x, wv = t >> 6, lane = t & 63;
  int n = blockIdx.x * 256 + t;
  bool act = n < N;
  int v[KK];
#pragma unroll
  for (int k = 0; k < KK; ++k) {
    v[k] = -1;
    if (k != 13 && act) v[k] = nbr[(size_t)k * N + n];
    unsigned long long m = __ballot(v[k] >= 0);
    if (lane == 0) wc[wv][k] = __popcll(m);
  }
  __syncthreads();
  if (t < KK) {
    int c0 = wc[0][t], c1 = wc[1][t], c2 = wc[2][t], c3 = wc[3][t];
    int tot = c0 + c1 + c2 + c3;
    int b = tot ? atomicAdd(&cursor[t], tot) : 0;
    wb[0][t] = b; wb[1][t] = b + c0; wb[2][t] = b + c0 + c1; wb[3][t] = b + c0 + c1 + c2;
  }
  __syncthreads();
  unsigned long long lt = (1ull << lane) - 1ull;
#pragma unroll
  for (int k = 0; k < KK; ++k) {
    if (k == 13) continue;
    bool val = v[k] >= 0;
    unsigned long long m = __ballot(val);
    if (!val) continue;
    int pos = wb[wv][k] + __popcll(m & lt);
    if (pos < kcnt[k]) {
      int slot = kbase[k] + pos;
      pairs[slot * 2]     = v[k];   // src
      pairs[slot * 2 + 1] = n;      // dst
    }
  }
}

// ---------------- GEMM microkernel: 128 rows x 64 cols from LDS ----------------
// Al stride 68 floats (row pad: adjacent rows 4 banks apart -> conflict-free b128)
__device__ __forceinline__ void gemm_micro(const float* Al, const float* Wl,
                                           int rowBase, int coBase, float acc[4][8])
{
#pragma unroll
  for (int i = 0; i < 4; ++i)
#pragma unroll
    for (int j = 0; j < 8; ++j) acc[i][j] = 0.f;
#pragma unroll 4
  for (int ci = 0; ci < 64; ci += 4) {
    float av[4][4];
    *(float4*)av[0] = *(const float4*)&Al[(rowBase     ) * 68 + ci];
    *(float4*)av[1] = *(const float4*)&Al[(rowBase +  8) * 68 + ci];
    *(float4*)av[2] = *(const float4*)&Al[(rowBase + 16) * 68 + ci];
    *(float4*)av[3] = *(const float4*)&Al[(rowBase + 24) * 68 + ci];
#pragma unroll
    for (int q = 0; q < 4; ++q) {
      float w8[8];
      *(float4*)&w8[0] = *(const float4*)&Wl[(ci + q) * 64 + coBase];
      *(float4*)&w8[4] = *(const float4*)&Wl[(ci + q) * 64 + coBase + 4];
#pragma unroll
      for (int i = 0; i < 4; ++i)
#pragma unroll
        for (int j = 0; j < 8; ++j)
          acc[i][j] = fmaf(av[i][q], w8[j], acc[i][j]);
    }
  }
}

// ---------------- per-k gather-GEMM-scatter (coalesced atomics) ----------------
template <int GATE>
__global__ __launch_bounds__(256) void scatter_k(
    const float* __restrict__ x, const float* __restrict__ Wfull,
    const int* __restrict__ pairs, const int* __restrict__ kcnt,
    const int* __restrict__ kbase, const int* __restrict__ seg2k,
    const int* __restrict__ nseg_p, const float* __restrict__ gate,
    const int* __restrict__ bidx, float* __restrict__ out)
{
  __shared__ float Wl[4096];
  __shared__ float Al[128 * 68];
  __shared__ int Sl[128], Dl[128];
  if ((int)blockIdx.x >= nseg_p[0]) return;
  int t = threadIdx.x;
  int k = seg2k[blockIdx.x];
  int pBase = blockIdx.x << 7;
  int pCnt = min(128, kcnt[k] - (pBase - kbase[k]));
  const float* Ws = Wfull + ((size_t)k << 12);
  for (int i = t; i < 4096; i += 256) Wl[i] = Ws[i];
  if (t < 128) {
    int s = -1, d = -1;
    if (t < pCnt) { s = pairs[(pBase + t) << 1]; d = pairs[((pBase + t) << 1) | 1]; }
    Sl[t] = s; Dl[t] = d;
  }
  __syncthreads();
  int rr = t >> 4, c4 = (t & 15) << 2;
  for (int it = 0; it < 8; ++it) {
    int r = (it << 4) + rr;
    float4 v = make_float4(0.f, 0.f, 0.f, 0.f);
    int src = Sl[r];
    if (src >= 0) {
      v = *(const float4*)(x + ((size_t)src << 6) + c4);
      if (GATE) {
        const float* g = gate + (bidx[src] << 6) + c4;
        v.x *= g[0]; v.y *= g[1]; v.z *= g[2]; v.w *= g[3];
      }
    }
    *(float4*)&Al[r * 68 + c4] = v;
  }
  __syncthreads();
  int wv = t >> 6, lane = t & 63, pg = lane >> 3, cg = lane & 7;
  int rowBase = (wv << 5) + pg, coBase = cg << 3;
  float acc[4][8];
  gemm_micro(Al, Wl, rowBase, coBase, acc);
  // round-trip result through LDS (reuse Al as O[128][68]) for coalesced atomics
  __syncthreads();
#pragma unroll
  for (int i = 0; i < 4; ++i) {
    int r = rowBase + (i << 3);
    *(float4*)&Al[r * 68 + coBase]     = *(const float4*)&acc[i][0];
    *(float4*)&Al[r * 68 + coBase + 4] = *(const float4*)&acc[i][4];
  }
  __syncthreads();
  // wave wv scatters rows [wv*32, wv*32+32): one atomic instr = 64 contiguous floats
  int w0 = wv << 5;
  for (int r2 = 0; r2 < 32; ++r2) {
    int r = w0 + r2;
    int d = Dl[r];
    if (d < 0) continue;
    float val = Al[r * 68 + lane];
    unsafeAtomicAdd(&out[((size_t)d << 6) + lane], val);
  }
}

// ---------------- dense center GEMM + fused epilogue ----------------
// MODE 0: conv1 (gated A, read hraw partial, BN+ReLU, write h in place)
// MODE 1: conv2 (A = h, +bias epilogue, write out; scatter adds afterwards)
template <int MODE>
__global__ __launch_bounds__(256) void center_epi(
    const float* __restrict__ x, const float* __restrict__ Wfull,
    const float* __restrict__ gate, const int* __restrict__ bidx,
    const float* __restrict__ ep_a, const float* __restrict__ ep_b,
    const float* hraw, float* __restrict__ out, int N)
{
  __shared__ float Wl[4096];
  __shared__ float Al[128 * 68];
  int t = threadIdx.x;
  int n0 = blockIdx.x << 7;
  int pCnt = min(128, N - n0);
  const float* Ws = Wfull + ((size_t)13 << 12);
  for (int i = t; i < 4096; i += 256) Wl[i] = Ws[i];
  int rr = t >> 4, c4 = (t & 15) << 2;
  for (int it = 0; it < 8; ++it) {
    int r = (it << 4) + rr;
    float4 v = make_float4(0.f, 0.f, 0.f, 0.f);
    if (r < pCnt) {
      int n = n0 + r;
      v = *(const float4*)(x + ((size_t)n << 6) + c4);
      if (MODE == 0) {
        const float* g = gate + (bidx[n] << 6) + c4;
        v.x *= g[0]; v.y *= g[1]; v.z *= g[2]; v.w *= g[3];
      }
    }
    *(float4*)&Al[r * 68 + c4] = v;
  }
  __syncthreads();
  int wv = t >> 6, lane = t & 63, pg = lane >> 3, cg = lane & 7;
  int rowBase = (wv << 5) + pg, coBase = cg << 3;
  float acc[4][8];
  gemm_micro(Al, Wl, rowBase, coBase, acc);
#pragma unroll
  for (int i = 0; i < 4; ++i) {
    int r = rowBase + (i << 3);
    if (r < pCnt) {
      size_t o = (((size_t)(n0 + r)) << 6) + coBase;
      if (MODE == 0) {
        float4 h0 = *(const float4*)&hraw[o];
        float4 h1 = *(const float4*)&hraw[o + 4];
        float4 r0, r1;
        r0.x = fmaxf(fmaf(acc[i][0] + h0.x, ep_a[coBase + 0], ep_b[coBase + 0]), 0.f);
        r0.y = fmaxf(fmaf(acc[i][1] + h0.y, ep_a[coBase + 1], ep_b[coBase + 1]), 0.f);
        r0.z = fmaxf(fmaf(acc[i][2] + h0.z, ep_a[coBase + 2], ep_b[coBase + 2]), 0.f);
        r0.w = fmaxf(fmaf(acc[i][3] + h0.w, ep_a[coBase + 3], ep_b[coBase + 3]), 0.f);
        r1.x = fmaxf(fmaf(acc[i][4] + h1.x, ep_a[coBase + 4], ep_b[coBase + 4]), 0.f);
        r1.y = fmaxf(fmaf(acc[i][5] + h1.y, ep_a[coBase + 5], ep_b[coBase + 5]), 0.f);
        r1.z = fmaxf(fmaf(acc[i][6] + h1.z, ep_a[coBase + 6], ep_b[coBase + 6]), 0.f);
        r1.w = fmaxf(fmaf(acc[i][7] + h1.w, ep_a[coBase + 7], ep_b[coBase + 7]), 0.f);
        *(float4*)&out[o]     = r0;
        *(float4*)&out[o + 4] = r1;
      } else {
        float4 r0, r1;
        r0.x = acc[i][0] + ep_b[coBase + 0];
        r0.y = acc[i][1] + ep_b[coBase + 1];
        r0.z = acc[i][2] + ep_b[coBase + 2];
        r0.w = acc[i][3] + ep_b[coBase + 3];
        r1.x = acc[i][4] + ep_b[coBase + 4];
        r1.y = acc[i][5] + ep_b[coBase + 5];
        r1.z = acc[i][6] + ep_b[coBase + 6];
        r1.w = acc[i][7] + ep_b[coBase + 7];
        *(float4*)&out[o]     = r0;
        *(float4*)&out[o + 4] = r1;
      }
    }
  }
}

// ---------------- round-1 fallback (small ws) ----------------
__global__ __launch_bounds__(256) void scale_w1(
    const float* __restrict__ w1, const float* __restrict__ gate,
    float* __restrict__ w1g)
{
  int b = blockIdx.x & 3, k = blockIdx.x >> 2;
  const float* src = w1 + ((size_t)k << 12);
  float* dst = w1g + (((size_t)(b * KK + k)) << 12);
  const float* g = gate + (b << 6);
  for (int it = 0; it < 16; ++it) {
    int pos = it * 256 + threadIdx.x;
    int ci = pos >> 6;
    dst[pos] = g[ci] * src[pos];
  }
}

template <int MODE>
__global__ __launch_bounds__(256) void spconv_kernel(
    const float* __restrict__ x, const int* __restrict__ nbr,
    const int* __restrict__ bidx, const float* __restrict__ W,
    const float* __restrict__ ep_a, const float* __restrict__ ep_b,
    float* __restrict__ out, int N)
{
  int wid = (int)((blockIdx.x * 256u + threadIdx.x) >> 6);
  if (wid >= N) return;
  int lane = threadIdx.x & 63;
  int n = __builtin_amdgcn_readfirstlane(wid);
  const float* Wb = W;
  if (MODE == 0) {
    int b = __builtin_amdgcn_readfirstlane(bidx[n]);
    Wb += (size_t)b * (KK * C * C);
  }
  float acc = 0.f;
#pragma unroll 1
  for (int k = 0; k < KK; ++k) {
    int idx = __builtin_amdgcn_readfirstlane(nbr[(size_t)k * N + n]);
    if (idx < 0) continue;
    const float* xr = x + ((size_t)idx << 6);
    const float* wr = Wb + (k << 12) + lane;
#pragma unroll
    for (int ci = 0; ci < C; ++ci) acc = fmaf(xr[ci], wr[ci << 6], acc);
  }
  float r;
  if (MODE == 0) r = fmaxf(fmaf(acc, ep_a[lane], ep_b[lane]), 0.f);
  else           r = acc + ep_b[lane];
  out[((size_t)n << 6) + lane] = r;
}

extern "C" void kernel_launch(void* const* d_in, const int* in_sizes, int n_in,
                              void* d_out, int out_size, void* d_ws, size_t ws_size,
                              hipStream_t stream) {
  const float* feats   = (const float*)d_in[0];
  const int*   nbr     = (const int*)  d_in[1];
  const int*   bidx    = (const int*)  d_in[2];
  const float* w_fc1   = (const float*)d_in[3];
  const float* b_fc1   = (const float*)d_in[4];
  const float* w_fc2   = (const float*)d_in[5];
  const float* b_fc2   = (const float*)d_in[6];
  const float* w_conv1 = (const float*)d_in[7];
  const float* bn_gamma= (const float*)d_in[8];
  const float* bn_beta = (const float*)d_in[9];
  const float* bn_mean = (const float*)d_in[10];
  const float* bn_var  = (const float*)d_in[11];
  const float* w_conv2 = (const float*)d_in[12];
  const float* b_conv2 = (const float*)d_in[13];

  int N = in_sizes[0] / C;
  float* ws      = (float*)d_ws;
  float* pooled  = ws;
  float* counts  = ws + 256;
  float* gate    = ws + 260;
  float* bnscale = ws + 516;
  float* bnshift = ws + 580;
  float* out     = (float*)d_out;

  size_t need = ((size_t)16384 + 2ull * PAIR_CAP + (size_t)N * C) * 4ull;

  if (ws_size >= need) {
    int* kcnt   = (int*)(ws + 644);
    int* kbase  = (int*)(ws + 671);
    int* cursor = (int*)(ws + 698);
    int* nseg   = (int*)(ws + 725);
    int* seg2k  = (int*)(ws + 1024);
    int* pairs  = (int*)(ws + 16384);
    float* h    = ws + 16384 + 2ull * PAIR_CAP;

    hipLaunchKernelGGL(init_ws, dim3(4), dim3(256), 0, stream, ws);
    hipLaunchKernelGGL(pool_kernel, dim3((N + 4095) / 4096), dim3(256), 0, stream,
                       feats, bidx, pooled, counts, N);
    hipLaunchKernelGGL(gate_kernel, dim3(1), dim3(256), 0, stream,
                       pooled, counts, w_fc1, b_fc1, w_fc2, b_fc2,
                       bn_gamma, bn_beta, bn_mean, bn_var, gate, bnscale, bnshift);
    hipLaunchKernelGGL(count_pairs, dim3((N + 255) / 256), dim3(256), 0, stream,
                       nbr, kcnt, N);
    hipLaunchKernelGGL(scan_pairs, dim3(1), dim3(32), 0, stream,
                       kcnt, kbase, cursor, nseg, (int)PAIR_CAP);
    hipLaunchKernelGGL(fill_seg2k, dim3(SEGMAX / 256), dim3(256), 0, stream,
                       kbase, nseg, seg2k);
    hipLaunchKernelGGL(fill_pairs, dim3((N + 255) / 256), dim3(256), 0, stream,
                       nbr, kbase, kcnt, cursor, pairs, N);
    hipLaunchKernelGGL(zero_h, dim3(2048), dim3(256), 0, stream,
                       (float4*)h, (long)N * (C / 4));
    // conv1: scatter non-center into h, then fused center + BN + ReLU (in place)
    hipLaunchKernelGGL((scatter_k<1>), dim3(SEGMAX), dim3(256), 0, stream,
                       feats, w_conv1, pairs, kcnt, kbase, seg2k, nseg, gate, bidx, h);
    hipLaunchKernelGGL((center_epi<0>), dim3((N + 127) / 128), dim3(256), 0, stream,
                       feats, w_conv1, gate, bidx, bnscale, bnshift, h, h, N);
    // conv2: center + bias writes out, then scatter non-center on top
    hipLaunchKernelGGL((center_epi<1>), dim3((N + 127) / 128), dim3(256), 0, stream,
                       h, w_conv2, nullptr, nullptr, nullptr, b_conv2, nullptr, out, N);
    hipLaunchKernelGGL((scatter_k<0>), dim3(SEGMAX), dim3(256), 0, stream,
                       h, w_conv2, pairs, kcnt, kbase, seg2k, nseg, nullptr, nullptr, out);
  } else {
    // round-1 fallback path
    float* w1g = ws + 1024;
    float* h   = ws + 1024 + BB * KK * C * C;
    hipLaunchKernelGGL(init_ws, dim3(4), dim3(256), 0, stream, ws);
    hipLaunchKernelGGL(pool_kernel, dim3((N + 4095) / 4096), dim3(256), 0, stream,
                       feats, bidx, pooled, counts, N);
    hipLaunchKernelGGL(gate_kernel, dim3(1), dim3(256), 0, stream,
                       pooled, counts, w_fc1, b_fc1, w_fc2, b_fc2,
                       bn_gamma, bn_beta, bn_mean, bn_var, gate, bnscale, bnshift);
    hipLaunchKernelGGL(scale_w1, dim3(KK * BB), dim3(256), 0, stream,
                       w_conv1, gate, w1g);
    hipLaunchKernelGGL((spconv_kernel<0>), dim3((N + 3) / 4), dim3(256), 0, stream,
                       feats, nbr, bidx, w1g, bnscale, bnshift, h, N);
    hipLaunchKernelGGL((spconv_kernel<1>), dim3((N + 3) / 4), dim3(256), 0, stream,
                       h, nbr, bidx, w_conv2, nullptr, b_conv2, out, N);
  }
}

// Round 5
// 1266.923 us; speedup vs baseline: 3.1872x; 1.3583x over previous
//
#include <hip/hip_runtime.h>

#define C  64
#define KK 27
#define BB 4

// ===================== fast-path ws layout (float offsets) =====================
//      0 : pooled[256]
//    256 : counts[4]
//    260 : gate[256]
//    516 : bnscale[64]
//    580 : bnshift[64]
//    644 : kcnt[27]   (int)
//    671 : kbase[27]  (int)
//    698 : cursor[27] (int)
//    725 : nseg[1]    (int)
//   1024 : seg2k[12288] (int)
//  16384 : pairs[2*PAIR_CAP] (int)  (src,dst interleaved)
//  16384+2*PAIR_CAP : h[N*C]
#define PAIR_CAP 1250000
#define SEGMAX   12288

__global__ __launch_bounds__(256) void init_ws(float* ws) {
  int t = blockIdx.x * 256 + threadIdx.x;
  if (t < 1024) ws[t] = 0.f;
}

__global__ __launch_bounds__(256) void zero_h(float4* __restrict__ p, long n4) {
  long i = (long)blockIdx.x * 256 + threadIdx.x;
  long stride = (long)gridDim.x * 256;
  float4 z = make_float4(0.f, 0.f, 0.f, 0.f);
  for (; i < n4; i += stride) p[i] = z;
}

// Grid-strided pooling: 16 threads per point row, float4 loads, shuffle+LDS reduce.
__global__ __launch_bounds__(256) void pool_kernel(
    const float4* __restrict__ x4, const int* __restrict__ bidx,
    float* __restrict__ pooled, float* __restrict__ counts, int N)
{
  int t = threadIdx.x;
  int g = t & 15;            // column group: floats [4g, 4g+4)
  int rowInBlk = t >> 4;     // 0..15
  int lane = t & 63, wv = t >> 6;
  float4 acc[BB];
#pragma unroll
  for (int b = 0; b < BB; ++b) acc[b] = make_float4(0.f, 0.f, 0.f, 0.f);
  int cnt[BB] = {0, 0, 0, 0};
  for (int n = blockIdx.x * 16 + rowInBlk; n < N; n += gridDim.x * 16) {
    int b = bidx[n];
    float4 v = x4[((size_t)n << 4) + g];
    if (b == 0)      { acc[0].x += v.x; acc[0].y += v.y; acc[0].z += v.z; acc[0].w += v.w; }
    else if (b == 1) { acc[1].x += v.x; acc[1].y += v.y; acc[1].z += v.z; acc[1].w += v.w; }
    else if (b == 2) { acc[2].x += v.x; acc[2].y += v.y; acc[2].z += v.z; acc[2].w += v.w; }
    else             { acc[3].x += v.x; acc[3].y += v.y; acc[3].z += v.z; acc[3].w += v.w; }
    if (g == 0) {
      if (b == 0) cnt[0]++; else if (b == 1) cnt[1]++;
      else if (b == 2) cnt[2]++; else cnt[3]++;
    }
  }
  // intra-wave reduce across lanes differing in bits 4,5 (same col group g)
#pragma unroll
  for (int b = 0; b < BB; ++b) {
    acc[b].x += __shfl_xor(acc[b].x, 16); acc[b].y += __shfl_xor(acc[b].y, 16);
    acc[b].z += __shfl_xor(acc[b].z, 16); acc[b].w += __shfl_xor(acc[b].w, 16);
    acc[b].x += __shfl_xor(acc[b].x, 32); acc[b].y += __shfl_xor(acc[b].y, 32);
    acc[b].z += __shfl_xor(acc[b].z, 32); acc[b].w += __shfl_xor(acc[b].w, 32);
    cnt[b] += __shfl_xor(cnt[b], 16);
    cnt[b] += __shfl_xor(cnt[b], 32);
  }
  __shared__ float red[4][BB][16][4];
  __shared__ int cred[4][BB];
  if (lane < 16) {
#pragma unroll
    for (int b = 0; b < BB; ++b) {
      red[wv][b][lane][0] = acc[b].x; red[wv][b][lane][1] = acc[b].y;
      red[wv][b][lane][2] = acc[b].z; red[wv][b][lane][3] = acc[b].w;
    }
    if (lane == 0) {
#pragma unroll
      for (int b = 0; b < BB; ++b) cred[wv][b] = cnt[b];
    }
  }
  __syncthreads();
  {
    int b = t >> 6, rem = t & 63;   // 256 threads = 4b x 16g x 4comp
    int gg = rem >> 2, comp = rem & 3;
    float s = red[0][b][gg][comp] + red[1][b][gg][comp] +
              red[2][b][gg][comp] + red[3][b][gg][comp];
    if (s != 0.f) atomicAdd(&pooled[b * C + (gg << 2) + comp], s);
  }
  if (t < BB) {
    int s = cred[0][t] + cred[1][t] + cred[2][t] + cred[3][t];
    if (s) atomicAdd(&counts[t], (float)s);
  }
}

__global__ __launch_bounds__(256) void gate_kernel(
    const float* __restrict__ pooled, const float* __restrict__ counts,
    const float* __restrict__ w_fc1, const float* __restrict__ b_fc1,
    const float* __restrict__ w_fc2, const float* __restrict__ b_fc2,
    const float* __restrict__ bn_gamma, const float* __restrict__ bn_beta,
    const float* __restrict__ bn_mean, const float* __restrict__ bn_var,
    float* __restrict__ gate, float* __restrict__ bnscale, float* __restrict__ bnshift)
{
  __shared__ float mean[BB * C];
  __shared__ float hh[BB * 16];
  int t = threadIdx.x;
  { int b = t >> 6; mean[t] = pooled[t] / counts[b]; }
  __syncthreads();
  if (t < BB * 16) {
    int b = t >> 4, r = t & 15;
    float s = b_fc1[r];
    for (int c = 0; c < C; ++c) s += mean[b * C + c] * w_fc1[c * 16 + r];
    hh[t] = fmaxf(s, 0.f);
  }
  __syncthreads();
  {
    int b = t >> 6, c = t & 63;
    float s = b_fc2[c];
    for (int r = 0; r < 16; ++r) s += hh[b * 16 + r] * w_fc2[r * 64 + c];
    gate[t] = 1.f / (1.f + expf(-s));
  }
  if (t < C) {
    float sc = bn_gamma[t] * rsqrtf(bn_var[t] + 1e-5f);
    bnscale[t] = sc;
    bnshift[t] = bn_beta[t] - bn_mean[t] * sc;
  }
}

// ---------------- pair-list build (ballot-based, no per-thread LDS atomics) ----------------
__global__ __launch_bounds__(256) void count_pairs(
    const int* __restrict__ nbr, int* __restrict__ kcnt, int N)
{
  __shared__ int wc[4][KK];
  int t = threadIdx.x, wv = t >> 6, lane = t & 63;
  int n = blockIdx.x * 256 + t;
  bool act = n < N;
#pragma unroll
  for (int k = 0; k < KK; ++k) {
    bool val = false;
    if (k != 13 && act) val = nbr[(size_t)k * N + n] >= 0;
    unsigned long long m = __ballot(val);
    if (lane == 0) wc[wv][k] = __popcll(m);
  }
  __syncthreads();
  if (t < KK) {
    int s = wc[0][t] + wc[1][t] + wc[2][t] + wc[3][t];
    if (s) atomicAdd(&kcnt[t], s);
  }
}

__global__ void scan_pairs(int* __restrict__ kcnt, int* __restrict__ kbase,
                           int* __restrict__ cursor, int* __restrict__ nseg, int cap)
{
  if (threadIdx.x == 0) {
    int off = 0;
    for (int k = 0; k < KK; ++k) {
      kbase[k] = off;
      int c = (k == 13) ? 0 : kcnt[k];
      int pad = (c + 127) & ~127;
      if (off + pad > cap) { kcnt[k] = 0; pad = 0; }   // safety clamp (never expected)
      off += pad;
    }
    int s = off >> 7;
    nseg[0] = (s > SEGMAX) ? SEGMAX : s;
  }
  if (threadIdx.x < KK) cursor[threadIdx.x] = 0;
}

__global__ __launch_bounds__(256) void fill_seg2k(
    const int* __restrict__ kbase, const int* __restrict__ nseg, int* __restrict__ seg2k)
{
  int j = blockIdx.x * 256 + threadIdx.x;
  if (j >= nseg[0]) return;
  int p = j << 7;
  int k = KK - 1;
#pragma unroll
  for (int q = 1; q < KK; ++q) { if (p < kbase[q]) { k = q - 1; break; } }
  seg2k[j] = k;
}

__global__ __launch_bounds__(256) void fill_pairs(
    const int* __restrict__ nbr, const int* __restrict__ kbase, const int* __restrict__ kcnt,
    int* __restrict__ cursor, int* __restrict__ pairs, int N)
{
  __shared__ int wc[4][KK];
  __shared__ int wb[4][KK];
  int t = threadIdx.x, wv = t >> 6, lane = t & 63;
  int n = blockIdx.x * 256 + t;
  bool act = n < N;
  int v[KK];
#pragma unroll
  for (int k = 0; k < KK; ++k) {
    v[k] = -1;
    if (k != 13 && act) v[k] = nbr[(size_t)k * N + n];
    unsigned long long m = __ballot(v[k] >= 0);
    if (lane == 0) wc[wv][k] = __popcll(m);
  }
  __syncthreads();
  if (t < KK) {
    int c0 = wc[0][t], c1 = wc[1][t], c2 = wc[2][t], c3 = wc[3][t];
    int tot = c0 + c1 + c2 + c3;
    int b = tot ? atomicAdd(&cursor[t], tot) : 0;
    wb[0][t] = b; wb[1][t] = b + c0; wb[2][t] = b + c0 + c1; wb[3][t] = b + c0 + c1 + c2;
  }
  __syncthreads();
  unsigned long long lt = (1ull << lane) - 1ull;
#pragma unroll
  for (int k = 0; k < KK; ++k) {
    if (k == 13) continue;
    bool val = v[k] >= 0;
    unsigned long long m = __ballot(val);
    if (!val) continue;
    int pos = wb[wv][k] + __popcll(m & lt);
    if (pos < kcnt[k]) {
      int slot = kbase[k] + pos;
      pairs[slot * 2]     = v[k];   // src
      pairs[slot * 2 + 1] = n;      // dst
    }
  }
}

// ---------------- GEMM microkernel: 128 rows x 64 cols from LDS ----------------
// Al stride 68 floats (row pad: adjacent rows 4 banks apart -> conflict-free b128)
__device__ __forceinline__ void gemm_micro(const float* Al, const float* Wl,
                                           int rowBase, int coBase, float acc[4][8])
{
#pragma unroll
  for (int i = 0; i < 4; ++i)
#pragma unroll
    for (int j = 0; j < 8; ++j) acc[i][j] = 0.f;
#pragma unroll 4
  for (int ci = 0; ci < 64; ci += 4) {
    float av[4][4];
    *(float4*)av[0] = *(const float4*)&Al[(rowBase     ) * 68 + ci];
    *(float4*)av[1] = *(const float4*)&Al[(rowBase +  8) * 68 + ci];
    *(float4*)av[2] = *(const float4*)&Al[(rowBase + 16) * 68 + ci];
    *(float4*)av[3] = *(const float4*)&Al[(rowBase + 24) * 68 + ci];
#pragma unroll
    for (int q = 0; q < 4; ++q) {
      float w8[8];
      *(float4*)&w8[0] = *(const float4*)&Wl[(ci + q) * 64 + coBase];
      *(float4*)&w8[4] = *(const float4*)&Wl[(ci + q) * 64 + coBase + 4];
#pragma unroll
      for (int i = 0; i < 4; ++i)
#pragma unroll
        for (int j = 0; j < 8; ++j)
          acc[i][j] = fmaf(av[i][q], w8[j], acc[i][j]);
    }
  }
}

// ---------------- per-k gather-GEMM-scatter (coalesced atomics) ----------------
template <int GATE>
__global__ __launch_bounds__(256) void scatter_k(
    const float* __restrict__ x, const float* __restrict__ Wfull,
    const int* __restrict__ pairs, const int* __restrict__ kcnt,
    const int* __restrict__ kbase, const int* __restrict__ seg2k,
    const int* __restrict__ nseg_p, const float* __restrict__ gate,
    const int* __restrict__ bidx, float* __restrict__ out)
{
  __shared__ float Wl[4096];
  __shared__ float Al[128 * 68];
  __shared__ int Sl[128], Dl[128];
  if ((int)blockIdx.x >= nseg_p[0]) return;
  int t = threadIdx.x;
  int k = seg2k[blockIdx.x];
  int pBase = blockIdx.x << 7;
  int pCnt = min(128, kcnt[k] - (pBase - kbase[k]));
  const float* Ws = Wfull + ((size_t)k << 12);
  for (int i = t; i < 4096; i += 256) Wl[i] = Ws[i];
  if (t < 128) {
    int s = -1, d = -1;
    if (t < pCnt) { s = pairs[(pBase + t) << 1]; d = pairs[((pBase + t) << 1) | 1]; }
    Sl[t] = s; Dl[t] = d;
  }
  __syncthreads();
  int rr = t >> 4, c4 = (t & 15) << 2;
  for (int it = 0; it < 8; ++it) {
    int r = (it << 4) + rr;
    float4 v = make_float4(0.f, 0.f, 0.f, 0.f);
    int src = Sl[r];
    if (src >= 0) {
      v = *(const float4*)(x + ((size_t)src << 6) + c4);
      if (GATE) {
        const float* g = gate + (bidx[src] << 6) + c4;
        v.x *= g[0]; v.y *= g[1]; v.z *= g[2]; v.w *= g[3];
      }
    }
    *(float4*)&Al[r * 68 + c4] = v;
  }
  __syncthreads();
  int wv = t >> 6, lane = t & 63, pg = lane >> 3, cg = lane & 7;
  int rowBase = (wv << 5) + pg, coBase = cg << 3;
  float acc[4][8];
  gemm_micro(Al, Wl, rowBase, coBase, acc);
  // round-trip result through LDS (reuse Al as O[128][68]) for coalesced atomics
  __syncthreads();
#pragma unroll
  for (int i = 0; i < 4; ++i) {
    int r = rowBase + (i << 3);
    *(float4*)&Al[r * 68 + coBase]     = *(const float4*)&acc[i][0];
    *(float4*)&Al[r * 68 + coBase + 4] = *(const float4*)&acc[i][4];
  }
  __syncthreads();
  // wave wv scatters rows [wv*32, wv*32+32): one atomic instr = 64 contiguous floats
  int w0 = wv << 5;
  for (int r2 = 0; r2 < 32; ++r2) {
    int r = w0 + r2;
    int d = Dl[r];
    if (d < 0) continue;
    float val = Al[r * 68 + lane];
    unsafeAtomicAdd(&out[((size_t)d << 6) + lane], val);
  }
}

// ---------------- dense center GEMM + fused epilogue ----------------
// MODE 0: conv1 (gated A, read hraw partial, BN+ReLU, write h in place)
// MODE 1: conv2 (A = h, +bias epilogue, write out; scatter adds afterwards)
template <int MODE>
__global__ __launch_bounds__(256) void center_epi(
    const float* __restrict__ x, const float* __restrict__ Wfull,
    const float* __restrict__ gate, const int* __restrict__ bidx,
    const float* __restrict__ ep_a, const float* __restrict__ ep_b,
    const float* hraw, float* __restrict__ out, int N)
{
  __shared__ float Wl[4096];
  __shared__ float Al[128 * 68];
  int t = threadIdx.x;
  int n0 = blockIdx.x << 7;
  int pCnt = min(128, N - n0);
  const float* Ws = Wfull + ((size_t)13 << 12);
  for (int i = t; i < 4096; i += 256) Wl[i] = Ws[i];
  int rr = t >> 4, c4 = (t & 15) << 2;
  for (int it = 0; it < 8; ++it) {
    int r = (it << 4) + rr;
    float4 v = make_float4(0.f, 0.f, 0.f, 0.f);
    if (r < pCnt) {
      int n = n0 + r;
      v = *(const float4*)(x + ((size_t)n << 6) + c4);
      if (MODE == 0) {
        const float* g = gate + (bidx[n] << 6) + c4;
        v.x *= g[0]; v.y *= g[1]; v.z *= g[2]; v.w *= g[3];
      }
    }
    *(float4*)&Al[r * 68 + c4] = v;
  }
  __syncthreads();
  int wv = t >> 6, lane = t & 63, pg = lane >> 3, cg = lane & 7;
  int rowBase = (wv << 5) + pg, coBase = cg << 3;
  float acc[4][8];
  gemm_micro(Al, Wl, rowBase, coBase, acc);
#pragma unroll
  for (int i = 0; i < 4; ++i) {
    int r = rowBase + (i << 3);
    if (r < pCnt) {
      size_t o = (((size_t)(n0 + r)) << 6) + coBase;
      if (MODE == 0) {
        float4 h0 = *(const float4*)&hraw[o];
        float4 h1 = *(const float4*)&hraw[o + 4];
        float4 r0, r1;
        r0.x = fmaxf(fmaf(acc[i][0] + h0.x, ep_a[coBase + 0], ep_b[coBase + 0]), 0.f);
        r0.y = fmaxf(fmaf(acc[i][1] + h0.y, ep_a[coBase + 1], ep_b[coBase + 1]), 0.f);
        r0.z = fmaxf(fmaf(acc[i][2] + h0.z, ep_a[coBase + 2], ep_b[coBase + 2]), 0.f);
        r0.w = fmaxf(fmaf(acc[i][3] + h0.w, ep_a[coBase + 3], ep_b[coBase + 3]), 0.f);
        r1.x = fmaxf(fmaf(acc[i][4] + h1.x, ep_a[coBase + 4], ep_b[coBase + 4]), 0.f);
        r1.y = fmaxf(fmaf(acc[i][5] + h1.y, ep_a[coBase + 5], ep_b[coBase + 5]), 0.f);
        r1.z = fmaxf(fmaf(acc[i][6] + h1.z, ep_a[coBase + 6], ep_b[coBase + 6]), 0.f);
        r1.w = fmaxf(fmaf(acc[i][7] + h1.w, ep_a[coBase + 7], ep_b[coBase + 7]), 0.f);
        *(float4*)&out[o]     = r0;
        *(float4*)&out[o + 4] = r1;
      } else {
        float4 r0, r1;
        r0.x = acc[i][0] + ep_b[coBase + 0];
        r0.y = acc[i][1] + ep_b[coBase + 1];
        r0.z = acc[i][2] + ep_b[coBase + 2];
        r0.w = acc[i][3] + ep_b[coBase + 3];
        r1.x = acc[i][4] + ep_b[coBase + 4];
        r1.y = acc[i][5] + ep_b[coBase + 5];
        r1.z = acc[i][6] + ep_b[coBase + 6];
        r1.w = acc[i][7] + ep_b[coBase + 7];
        *(float4*)&out[o]     = r0;
        *(float4*)&out[o + 4] = r1;
      }
    }
  }
}

// ---------------- round-1 fallback (small ws) ----------------
__global__ __launch_bounds__(256) void scale_w1(
    const float* __restrict__ w1, const float* __restrict__ gate,
    float* __restrict__ w1g)
{
  int b = blockIdx.x & 3, k = blockIdx.x >> 2;
  const float* src = w1 + ((size_t)k << 12);
  float* dst = w1g + (((size_t)(b * KK + k)) << 12);
  const float* g = gate + (b << 6);
  for (int it = 0; it < 16; ++it) {
    int pos = it * 256 + threadIdx.x;
    int ci = pos >> 6;
    dst[pos] = g[ci] * src[pos];
  }
}

template <int MODE>
__global__ __launch_bounds__(256) void spconv_kernel(
    const float* __restrict__ x, const int* __restrict__ nbr,
    const int* __restrict__ bidx, const float* __restrict__ W,
    const float* __restrict__ ep_a, const float* __restrict__ ep_b,
    float* __restrict__ out, int N)
{
  int wid = (int)((blockIdx.x * 256u + threadIdx.x) >> 6);
  if (wid >= N) return;
  int lane = threadIdx.x & 63;
  int n = __builtin_amdgcn_readfirstlane(wid);
  const float* Wb = W;
  if (MODE == 0) {
    int b = __builtin_amdgcn_readfirstlane(bidx[n]);
    Wb += (size_t)b * (KK * C * C);
  }
  float acc = 0.f;
#pragma unroll 1
  for (int k = 0; k < KK; ++k) {
    int idx = __builtin_amdgcn_readfirstlane(nbr[(size_t)k * N + n]);
    if (idx < 0) continue;
    const float* xr = x + ((size_t)idx << 6);
    const float* wr = Wb + (k << 12) + lane;
#pragma unroll
    for (int ci = 0; ci < C; ++ci) acc = fmaf(xr[ci], wr[ci << 6], acc);
  }
  float r;
  if (MODE == 0) r = fmaxf(fmaf(acc, ep_a[lane], ep_b[lane]), 0.f);
  else           r = acc + ep_b[lane];
  out[((size_t)n << 6) + lane] = r;
}

extern "C" void kernel_launch(void* const* d_in, const int* in_sizes, int n_in,
                              void* d_out, int out_size, void* d_ws, size_t ws_size,
                              hipStream_t stream) {
  const float* feats   = (const float*)d_in[0];
  const int*   nbr     = (const int*)  d_in[1];
  const int*   bidx    = (const int*)  d_in[2];
  const float* w_fc1   = (const float*)d_in[3];
  const float* b_fc1   = (const float*)d_in[4];
  const float* w_fc2   = (const float*)d_in[5];
  const float* b_fc2   = (const float*)d_in[6];
  const float* w_conv1 = (const float*)d_in[7];
  const float* bn_gamma= (const float*)d_in[8];
  const float* bn_beta = (const float*)d_in[9];
  const float* bn_mean = (const float*)d_in[10];
  const float* bn_var  = (const float*)d_in[11];
  const float* w_conv2 = (const float*)d_in[12];
  const float* b_conv2 = (const float*)d_in[13];

  int N = in_sizes[0] / C;
  float* ws      = (float*)d_ws;
  float* pooled  = ws;
  float* counts  = ws + 256;
  float* gate    = ws + 260;
  float* bnscale = ws + 516;
  float* bnshift = ws + 580;
  float* out     = (float*)d_out;

  size_t need = ((size_t)16384 + 2ull * PAIR_CAP + (size_t)N * C) * 4ull;

  if (ws_size >= need) {
    int* kcnt   = (int*)(ws + 644);
    int* kbase  = (int*)(ws + 671);
    int* cursor = (int*)(ws + 698);
    int* nseg   = (int*)(ws + 725);
    int* seg2k  = (int*)(ws + 1024);
    int* pairs  = (int*)(ws + 16384);
    float* h    = ws + 16384 + 2ull * PAIR_CAP;

    hipLaunchKernelGGL(init_ws, dim3(4), dim3(256), 0, stream, ws);
    hipLaunchKernelGGL(pool_kernel, dim3(1024), dim3(256), 0, stream,
                       (const float4*)feats, bidx, pooled, counts, N);
    hipLaunchKernelGGL(gate_kernel, dim3(1), dim3(256), 0, stream,
                       pooled, counts, w_fc1, b_fc1, w_fc2, b_fc2,
                       bn_gamma, bn_beta, bn_mean, bn_var, gate, bnscale, bnshift);
    hipLaunchKernelGGL(count_pairs, dim3((N + 255) / 256), dim3(256), 0, stream,
                       nbr, kcnt, N);
    hipLaunchKernelGGL(scan_pairs, dim3(1), dim3(32), 0, stream,
                       kcnt, kbase, cursor, nseg, (int)PAIR_CAP);
    hipLaunchKernelGGL(fill_seg2k, dim3(SEGMAX / 256), dim3(256), 0, stream,
                       kbase, nseg, seg2k);
    hipLaunchKernelGGL(fill_pairs, dim3((N + 255) / 256), dim3(256), 0, stream,
                       nbr, kbase, kcnt, cursor, pairs, N);
    hipLaunchKernelGGL(zero_h, dim3(2048), dim3(256), 0, stream,
                       (float4*)h, (long)N * (C / 4));
    // conv1: scatter non-center into h, then fused center + BN + ReLU (in place)
    hipLaunchKernelGGL((scatter_k<1>), dim3(SEGMAX), dim3(256), 0, stream,
                       feats, w_conv1, pairs, kcnt, kbase, seg2k, nseg, gate, bidx, h);
    hipLaunchKernelGGL((center_epi<0>), dim3((N + 127) / 128), dim3(256), 0, stream,
                       feats, w_conv1, gate, bidx, bnscale, bnshift, h, h, N);
    // conv2: center + bias writes out, then scatter non-center on top
    hipLaunchKernelGGL((center_epi<1>), dim3((N + 127) / 128), dim3(256), 0, stream,
                       h, w_conv2, nullptr, nullptr, nullptr, b_conv2, nullptr, out, N);
    hipLaunchKernelGGL((scatter_k<0>), dim3(SEGMAX), dim3(256), 0, stream,
                       h, w_conv2, pairs, kcnt, kbase, seg2k, nseg, nullptr, nullptr, out);
  } else {
    // round-1 fallback path
    float* w1g = ws + 1024;
    float* h   = ws + 1024 + BB * KK * C * C;
    hipLaunchKernelGGL(init_ws, dim3(4), dim3(256), 0, stream, ws);
    hipLaunchKernelGGL(pool_kernel, dim3(1024), dim3(256), 0, stream,
                       (const float4*)feats, bidx, pooled, counts, N);
    hipLaunchKernelGGL(gate_kernel, dim3(1), dim3(256), 0, stream,
                       pooled, counts, w_fc1, b_fc1, w_fc2, b_fc2,
                       bn_gamma, bn_beta, bn_mean, bn_var, gate, bnscale, bnshift);
    hipLaunchKernelGGL(scale_w1, dim3(KK * BB), dim3(256), 0, stream,
                       w_conv1, gate, w1g);
    hipLaunchKernelGGL((spconv_kernel<0>), dim3((N + 3) / 4), dim3(256), 0, stream,
                       feats, nbr, bidx, w1g, bnscale, bnshift, h, N);
    hipLaunchKernelGGL((spconv_kernel<1>), dim3((N + 3) / 4), dim3(256), 0, stream,
                       h, nbr, bidx, w_conv2, nullptr, b_conv2, out, N);
  }
}

// Round 7
// 999.845 us; speedup vs baseline: 4.0386x; 1.2671x over previous
//
#include <hip/hip_runtime.h>

#define C  64
#define KK 27
#define BB 4

// ===================== fast-path ws layout (float offsets) =====================
//      0 : pooled[256]
//    256 : counts[4]
//    260 : gate[256]
//    516 : bnscale[64]
//    580 : bnshift[64]
//    644 : kcnt[27]   (int)
//    671 : kbase[27]  (int)
//    698 : cursor[27] (int)
//    725 : nseg[1]    (int)
//   1024 : seg2k[12288] (int)
//  16384 : pairs[2*PAIR_CAP] (int)  (src,dst interleaved)
//  16384+2*PAIR_CAP : h[N*C]
#define PAIR_CAP 1250000
#define SEGMAX   12288

__global__ __launch_bounds__(256) void init_ws(float* ws) {
  int t = blockIdx.x * 256 + threadIdx.x;
  if (t < 1024) ws[t] = 0.f;
}

__global__ __launch_bounds__(256) void zero_h(float4* __restrict__ p, long n4) {
  long i = (long)blockIdx.x * 256 + threadIdx.x;
  long stride = (long)gridDim.x * 256;
  float4 z = make_float4(0.f, 0.f, 0.f, 0.f);
  for (; i < n4; i += stride) p[i] = z;
}

// Grid-strided pooling: 16 threads per point row, float4 loads, shuffle+LDS reduce.
__global__ __launch_bounds__(256) void pool_kernel(
    const float4* __restrict__ x4, const int* __restrict__ bidx,
    float* __restrict__ pooled, float* __restrict__ counts, int N)
{
  int t = threadIdx.x;
  int g = t & 15;            // column group: floats [4g, 4g+4)
  int rowInBlk = t >> 4;     // 0..15
  int lane = t & 63, wv = t >> 6;
  float4 acc[BB];
#pragma unroll
  for (int b = 0; b < BB; ++b) acc[b] = make_float4(0.f, 0.f, 0.f, 0.f);
  int cnt[BB] = {0, 0, 0, 0};
  for (int n = blockIdx.x * 16 + rowInBlk; n < N; n += gridDim.x * 16) {
    int b = bidx[n];
    float4 v = x4[((size_t)n << 4) + g];
    if (b == 0)      { acc[0].x += v.x; acc[0].y += v.y; acc[0].z += v.z; acc[0].w += v.w; }
    else if (b == 1) { acc[1].x += v.x; acc[1].y += v.y; acc[1].z += v.z; acc[1].w += v.w; }
    else if (b == 2) { acc[2].x += v.x; acc[2].y += v.y; acc[2].z += v.z; acc[2].w += v.w; }
    else             { acc[3].x += v.x; acc[3].y += v.y; acc[3].z += v.z; acc[3].w += v.w; }
    if (g == 0) {
      if (b == 0) cnt[0]++; else if (b == 1) cnt[1]++;
      else if (b == 2) cnt[2]++; else cnt[3]++;
    }
  }
#pragma unroll
  for (int b = 0; b < BB; ++b) {
    acc[b].x += __shfl_xor(acc[b].x, 16); acc[b].y += __shfl_xor(acc[b].y, 16);
    acc[b].z += __shfl_xor(acc[b].z, 16); acc[b].w += __shfl_xor(acc[b].w, 16);
    acc[b].x += __shfl_xor(acc[b].x, 32); acc[b].y += __shfl_xor(acc[b].y, 32);
    acc[b].z += __shfl_xor(acc[b].z, 32); acc[b].w += __shfl_xor(acc[b].w, 32);
    cnt[b] += __shfl_xor(cnt[b], 16);
    cnt[b] += __shfl_xor(cnt[b], 32);
  }
  __shared__ float red[4][BB][16][4];
  __shared__ int cred[4][BB];
  if (lane < 16) {
#pragma unroll
    for (int b = 0; b < BB; ++b) {
      red[wv][b][lane][0] = acc[b].x; red[wv][b][lane][1] = acc[b].y;
      red[wv][b][lane][2] = acc[b].z; red[wv][b][lane][3] = acc[b].w;
    }
    if (lane == 0) {
#pragma unroll
      for (int b = 0; b < BB; ++b) cred[wv][b] = cnt[b];
    }
  }
  __syncthreads();
  {
    int b = t >> 6, rem = t & 63;   // 256 threads = 4b x 16g x 4comp
    int gg = rem >> 2, comp = rem & 3;
    float s = red[0][b][gg][comp] + red[1][b][gg][comp] +
              red[2][b][gg][comp] + red[3][b][gg][comp];
    if (s != 0.f) atomicAdd(&pooled[b * C + (gg << 2) + comp], s);
  }
  if (t < BB) {
    int s = cred[0][t] + cred[1][t] + cred[2][t] + cred[3][t];
    if (s) atomicAdd(&counts[t], (float)s);
  }
}

__global__ __launch_bounds__(256) void gate_kernel(
    const float* __restrict__ pooled, const float* __restrict__ counts,
    const float* __restrict__ w_fc1, const float* __restrict__ b_fc1,
    const float* __restrict__ w_fc2, const float* __restrict__ b_fc2,
    const float* __restrict__ bn_gamma, const float* __restrict__ bn_beta,
    const float* __restrict__ bn_mean, const float* __restrict__ bn_var,
    float* __restrict__ gate, float* __restrict__ bnscale, float* __restrict__ bnshift)
{
  __shared__ float mean[BB * C];
  __shared__ float hh[BB * 16];
  int t = threadIdx.x;
  { int b = t >> 6; mean[t] = pooled[t] / counts[b]; }
  __syncthreads();
  if (t < BB * 16) {
    int b = t >> 4, r = t & 15;
    float s = b_fc1[r];
    for (int c = 0; c < C; ++c) s += mean[b * C + c] * w_fc1[c * 16 + r];
    hh[t] = fmaxf(s, 0.f);
  }
  __syncthreads();
  {
    int b = t >> 6, c = t & 63;
    float s = b_fc2[c];
    for (int r = 0; r < 16; ++r) s += hh[b * 16 + r] * w_fc2[r * 64 + c];
    gate[t] = 1.f / (1.f + expf(-s));
  }
  if (t < C) {
    float sc = bn_gamma[t] * rsqrtf(bn_var[t] + 1e-5f);
    bnscale[t] = sc;
    bnshift[t] = bn_beta[t] - bn_mean[t] * sc;
  }
}

// ---------------- pair-list build (ballot-based) ----------------
__global__ __launch_bounds__(256) void count_pairs(
    const int* __restrict__ nbr, int* __restrict__ kcnt, int N)
{
  __shared__ int wc[4][KK];
  int t = threadIdx.x, wv = t >> 6, lane = t & 63;
  int n = blockIdx.x * 256 + t;
  bool act = n < N;
#pragma unroll
  for (int k = 0; k < KK; ++k) {
    bool val = false;
    if (k != 13 && act) val = nbr[(size_t)k * N + n] >= 0;
    unsigned long long m = __ballot(val);
    if (lane == 0) wc[wv][k] = __popcll(m);
  }
  __syncthreads();
  if (t < KK) {
    int s = wc[0][t] + wc[1][t] + wc[2][t] + wc[3][t];
    if (s) atomicAdd(&kcnt[t], s);
  }
}

__global__ void scan_pairs(int* __restrict__ kcnt, int* __restrict__ kbase,
                           int* __restrict__ cursor, int* __restrict__ nseg, int cap)
{
  if (threadIdx.x == 0) {
    int off = 0;
    for (int k = 0; k < KK; ++k) {
      kbase[k] = off;
      int c = (k == 13) ? 0 : kcnt[k];
      int pad = (c + 127) & ~127;
      if (off + pad > cap) { kcnt[k] = 0; pad = 0; }   // safety clamp (never expected)
      off += pad;
    }
    int s = off >> 7;
    nseg[0] = (s > SEGMAX) ? SEGMAX : s;
  }
  if (threadIdx.x < KK) cursor[threadIdx.x] = 0;
}

__global__ __launch_bounds__(256) void fill_seg2k(
    const int* __restrict__ kbase, const int* __restrict__ nseg, int* __restrict__ seg2k)
{
  int j = blockIdx.x * 256 + threadIdx.x;
  if (j >= nseg[0]) return;
  int p = j << 7;
  int k = KK - 1;
#pragma unroll
  for (int q = 1; q < KK; ++q) { if (p < kbase[q]) { k = q - 1; break; } }
  seg2k[j] = k;
}

__global__ __launch_bounds__(256) void fill_pairs(
    const int* __restrict__ nbr, const int* __restrict__ kbase, const int* __restrict__ kcnt,
    int* __restrict__ cursor, int* __restrict__ pairs, int N)
{
  __shared__ int wc[4][KK];
  __shared__ int wb[4][KK];
  int t = threadIdx.x, wv = t >> 6, lane = t & 63;
  int n = blockIdx.x * 256 + t;
  bool act = n < N;
  int v[KK];
#pragma unroll
  for (int k = 0; k < KK; ++k) {
    v[k] = -1;
    if (k != 13 && act) v[k] = nbr[(size_t)k * N + n];
    unsigned long long m = __ballot(v[k] >= 0);
    if (lane == 0) wc[wv][k] = __popcll(m);
  }
  __syncthreads();
  if (t < KK) {
    int c0 = wc[0][t], c1 = wc[1][t], c2 = wc[2][t], c3 = wc[3][t];
    int tot = c0 + c1 + c2 + c3;
    int b = tot ? atomicAdd(&cursor[t], tot) : 0;
    wb[0][t] = b; wb[1][t] = b + c0; wb[2][t] = b + c0 + c1; wb[3][t] = b + c0 + c1 + c2;
  }
  __syncthreads();
  unsigned long long lt = (1ull << lane) - 1ull;
#pragma unroll
  for (int k = 0; k < KK; ++k) {
    if (k == 13) continue;
    bool val = v[k] >= 0;
    unsigned long long m = __ballot(val);
    if (!val) continue;
    int pos = wb[wv][k] + __popcll(m & lt);
    if (pos < kcnt[k]) {
      int slot = kbase[k] + pos;
      pairs[slot * 2]     = v[k];   // src
      pairs[slot * 2 + 1] = n;      // dst
    }
  }
}

// ---------------- GEMM microkernel (512-thread): 128 rows x 64 cols ----------------
// 8 waves, wave wv owns rows [wv*16, wv*16+16); thread (pg,cg): rows {base, base+8},
// cols [cg*8, cg*8+8). Al stride 68 floats (4-bank row skew -> conflict-free b128).
__device__ __forceinline__ void gemm_micro2(const float* Al, const float* Wl,
                                            int rowBase, int coBase, float acc[2][8])
{
#pragma unroll
  for (int i = 0; i < 2; ++i)
#pragma unroll
    for (int j = 0; j < 8; ++j) acc[i][j] = 0.f;
#pragma unroll 4
  for (int ci = 0; ci < 64; ci += 4) {
    float av[2][4];
    *(float4*)av[0] = *(const float4*)&Al[(rowBase    ) * 68 + ci];
    *(float4*)av[1] = *(const float4*)&Al[(rowBase + 8) * 68 + ci];
#pragma unroll
    for (int q = 0; q < 4; ++q) {
      float w8[8];
      *(float4*)&w8[0] = *(const float4*)&Wl[(ci + q) * 64 + coBase];
      *(float4*)&w8[4] = *(const float4*)&Wl[(ci + q) * 64 + coBase + 4];
#pragma unroll
      for (int i = 0; i < 2; ++i)
#pragma unroll
        for (int j = 0; j < 8; ++j)
          acc[i][j] = fmaf(av[i][q], w8[j], acc[i][j]);
    }
  }
}

// ---------------- per-k gather-GEMM-scatter (coalesced atomics, 512 thr) ----------------
template <int GATE>
__global__ __launch_bounds__(512) void scatter_k(
    const float* __restrict__ x, const float* __restrict__ Wfull,
    const int* __restrict__ pairs, const int* __restrict__ kcnt,
    const int* __restrict__ kbase, const int* __restrict__ seg2k,
    const int* __restrict__ nseg_p, const float* __restrict__ gate,
    const int* __restrict__ bidx, float* __restrict__ out)
{
  __shared__ float Wl[4096];
  __shared__ float Al[128 * 68];
  __shared__ int Sl[128], Dl[128];
  if ((int)blockIdx.x >= nseg_p[0]) return;
  int t = threadIdx.x;
  int k = seg2k[blockIdx.x];
  int pBase = blockIdx.x << 7;
  int pCnt = min(128, kcnt[k] - (pBase - kbase[k]));
  const float* Ws = Wfull + ((size_t)k << 12);
  for (int i = t; i < 4096; i += 512) Wl[i] = Ws[i];
  if (t < 128) {
    int s = -1, d = -1;
    if (t < pCnt) { s = pairs[(pBase + t) << 1]; d = pairs[((pBase + t) << 1) | 1]; }
    Sl[t] = s; Dl[t] = d;
  }
  __syncthreads();
  int rr = t >> 4, c4 = (t & 15) << 2;   // rr 0..31
  for (int it = 0; it < 4; ++it) {
    int r = (it << 5) + rr;
    float4 v = make_float4(0.f, 0.f, 0.f, 0.f);
    int src = Sl[r];
    if (src >= 0) {
      v = *(const float4*)(x + ((size_t)src << 6) + c4);
      if (GATE) {
        const float* g = gate + (bidx[src] << 6) + c4;
        v.x *= g[0]; v.y *= g[1]; v.z *= g[2]; v.w *= g[3];
      }
    }
    *(float4*)&Al[r * 68 + c4] = v;
  }
  __syncthreads();
  int wv = t >> 6, lane = t & 63, pg = lane >> 3, cg = lane & 7;
  int rowBase = (wv << 4) + pg, coBase = cg << 3;
  float acc[2][8];
  gemm_micro2(Al, Wl, rowBase, coBase, acc);
  // round-trip result through LDS (reuse Al as O[128][68]) for coalesced atomics
  __syncthreads();
#pragma unroll
  for (int i = 0; i < 2; ++i) {
    int r = rowBase + (i << 3);
    *(float4*)&Al[r * 68 + coBase]     = *(const float4*)&acc[i][0];
    *(float4*)&Al[r * 68 + coBase + 4] = *(const float4*)&acc[i][4];
  }
  __syncthreads();
  // wave wv scatters rows [wv*16, wv*16+16): one atomic instr = 64 contiguous floats
  int w0 = wv << 4;
  for (int r2 = 0; r2 < 16; ++r2) {
    int r = w0 + r2;
    int d = Dl[r];
    if (d < 0) continue;
    float val = Al[r * 68 + lane];
    unsafeAtomicAdd(&out[((size_t)d << 6) + lane], val);
  }
}

// ---------------- dense center GEMM + fused epilogue (512 thr) ----------------
// MODE 0: conv1 (gated A, read hraw partial, BN+ReLU, write h in place)
// MODE 1: conv2 (A = h, +bias epilogue, write out; scatter adds afterwards)
template <int MODE>
__global__ __launch_bounds__(512) void center_epi(
    const float* __restrict__ x, const float* __restrict__ Wfull,
    const float* __restrict__ gate, const int* __restrict__ bidx,
    const float* __restrict__ ep_a, const float* __restrict__ ep_b,
    const float* hraw, float* __restrict__ out, int N)
{
  __shared__ float Wl[4096];
  __shared__ float Al[128 * 68];
  int t = threadIdx.x;
  int n0 = blockIdx.x << 7;
  int pCnt = min(128, N - n0);
  const float* Ws = Wfull + ((size_t)13 << 12);
  for (int i = t; i < 4096; i += 512) Wl[i] = Ws[i];
  int rr = t >> 4, c4 = (t & 15) << 2;
  for (int it = 0; it < 4; ++it) {
    int r = (it << 5) + rr;
    float4 v = make_float4(0.f, 0.f, 0.f, 0.f);
    if (r < pCnt) {
      int n = n0 + r;
      v = *(const float4*)(x + ((size_t)n << 6) + c4);
      if (MODE == 0) {
        const float* g = gate + (bidx[n] << 6) + c4;
        v.x *= g[0]; v.y *= g[1]; v.z *= g[2]; v.w *= g[3];
      }
    }
    *(float4*)&Al[r * 68 + c4] = v;
  }
  __syncthreads();
  int wv = t >> 6, lane = t & 63, pg = lane >> 3, cg = lane & 7;
  int rowBase = (wv << 4) + pg, coBase = cg << 3;
  float acc[2][8];
  gemm_micro2(Al, Wl, rowBase, coBase, acc);
#pragma unroll
  for (int i = 0; i < 2; ++i) {
    int r = rowBase + (i << 3);
    if (r < pCnt) {
      size_t o = (((size_t)(n0 + r)) << 6) + coBase;
      if (MODE == 0) {
        float4 h0 = *(const float4*)&hraw[o];
        float4 h1 = *(const float4*)&hraw[o + 4];
        float4 r0, r1;
        r0.x = fmaxf(fmaf(acc[i][0] + h0.x, ep_a[coBase + 0], ep_b[coBase + 0]), 0.f);
        r0.y = fmaxf(fmaf(acc[i][1] + h0.y, ep_a[coBase + 1], ep_b[coBase + 1]), 0.f);
        r0.z = fmaxf(fmaf(acc[i][2] + h0.z, ep_a[coBase + 2], ep_b[coBase + 2]), 0.f);
        r0.w = fmaxf(fmaf(acc[i][3] + h0.w, ep_a[coBase + 3], ep_b[coBase + 3]), 0.f);
        r1.x = fmaxf(fmaf(acc[i][4] + h1.x, ep_a[coBase + 4], ep_b[coBase + 4]), 0.f);
        r1.y = fmaxf(fmaf(acc[i][5] + h1.y, ep_a[coBase + 5], ep_b[coBase + 5]), 0.f);
        r1.z = fmaxf(fmaf(acc[i][6] + h1.z, ep_a[coBase + 6], ep_b[coBase + 6]), 0.f);
        r1.w = fmaxf(fmaf(acc[i][7] + h1.w, ep_a[coBase + 7], ep_b[coBase + 7]), 0.f);
        *(float4*)&out[o]     = r0;
        *(float4*)&out[o + 4] = r1;
      } else {
        float4 r0, r1;
        r0.x = acc[i][0] + ep_b[coBase + 0];
        r0.y = acc[i][1] + ep_b[coBase + 1];
        r0.z = acc[i][2] + ep_b[coBase + 2];
        r0.w = acc[i][3] + ep_b[coBase + 3];
        r1.x = acc[i][4] + ep_b[coBase + 4];
        r1.y = acc[i][5] + ep_b[coBase + 5];
        r1.z = acc[i][6] + ep_b[coBase + 6];
        r1.w = acc[i][7] + ep_b[coBase + 7];
        *(float4*)&out[o]     = r0;
        *(float4*)&out[o + 4] = r1;
      }
    }
  }
}

// ---------------- round-1 fallback (small ws) ----------------
__global__ __launch_bounds__(256) void scale_w1(
    const float* __restrict__ w1, const float* __restrict__ gate,
    float* __restrict__ w1g)
{
  int b = blockIdx.x & 3, k = blockIdx.x >> 2;
  const float* src = w1 + ((size_t)k << 12);
  float* dst = w1g + (((size_t)(b * KK + k)) << 12);
  const float* g = gate + (b << 6);
  for (int it = 0; it < 16; ++it) {
    int pos = it * 256 + threadIdx.x;
    int ci = pos >> 6;
    dst[pos] = g[ci] * src[pos];
  }
}

template <int MODE>
__global__ __launch_bounds__(256) void spconv_kernel(
    const float* __restrict__ x, const int* __restrict__ nbr,
    const int* __restrict__ bidx, const float* __restrict__ W,
    const float* __restrict__ ep_a, const float* __restrict__ ep_b,
    float* __restrict__ out, int N)
{
  int wid = (int)((blockIdx.x * 256u + threadIdx.x) >> 6);
  if (wid >= N) return;
  int lane = threadIdx.x & 63;
  int n = __builtin_amdgcn_readfirstlane(wid);
  const float* Wb = W;
  if (MODE == 0) {
    int b = __builtin_amdgcn_readfirstlane(bidx[n]);
    Wb += (size_t)b * (KK * C * C);
  }
  float acc = 0.f;
#pragma unroll 1
  for (int k = 0; k < KK; ++k) {
    int idx = __builtin_amdgcn_readfirstlane(nbr[(size_t)k * N + n]);
    if (idx < 0) continue;
    const float* xr = x + ((size_t)idx << 6);
    const float* wr = Wb + (k << 12) + lane;
#pragma unroll
    for (int ci = 0; ci < C; ++ci) acc = fmaf(xr[ci], wr[ci << 6], acc);
  }
  float r;
  if (MODE == 0) r = fmaxf(fmaf(acc, ep_a[lane], ep_b[lane]), 0.f);
  else           r = acc + ep_b[lane];
  out[((size_t)n << 6) + lane] = r;
}

extern "C" void kernel_launch(void* const* d_in, const int* in_sizes, int n_in,
                              void* d_out, int out_size, void* d_ws, size_t ws_size,
                              hipStream_t stream) {
  const float* feats   = (const float*)d_in[0];
  const int*   nbr     = (const int*)  d_in[1];
  const int*   bidx    = (const int*)  d_in[2];
  const float* w_fc1   = (const float*)d_in[3];
  const float* b_fc1   = (const float*)d_in[4];
  const float* w_fc2   = (const float*)d_in[5];
  const float* b_fc2   = (const float*)d_in[6];
  const float* w_conv1 = (const float*)d_in[7];
  const float* bn_gamma= (const float*)d_in[8];
  const float* bn_beta = (const float*)d_in[9];
  const float* bn_mean = (const float*)d_in[10];
  const float* bn_var  = (const float*)d_in[11];
  const float* w_conv2 = (const float*)d_in[12];
  const float* b_conv2 = (const float*)d_in[13];

  int N = in_sizes[0] / C;
  float* ws      = (float*)d_ws;
  float* pooled  = ws;
  float* counts  = ws + 256;
  float* gate    = ws + 260;
  float* bnscale = ws + 516;
  float* bnshift = ws + 580;
  float* out     = (float*)d_out;

  size_t need = ((size_t)16384 + 2ull * PAIR_CAP + (size_t)N * C) * 4ull;

  if (ws_size >= need) {
    int* kcnt   = (int*)(ws + 644);
    int* kbase  = (int*)(ws + 671);
    int* cursor = (int*)(ws + 698);
    int* nseg   = (int*)(ws + 725);
    int* seg2k  = (int*)(ws + 1024);
    int* pairs  = (int*)(ws + 16384);
    float* h    = ws + 16384 + 2ull * PAIR_CAP;

    hipLaunchKernelGGL(init_ws, dim3(4), dim3(256), 0, stream, ws);
    hipLaunchKernelGGL(pool_kernel, dim3(1024), dim3(256), 0, stream,
                       (const float4*)feats, bidx, pooled, counts, N);
    hipLaunchKernelGGL(gate_kernel, dim3(1), dim3(256), 0, stream,
                       pooled, counts, w_fc1, b_fc1, w_fc2, b_fc2,
                       bn_gamma, bn_beta, bn_mean, bn_var, gate, bnscale, bnshift);
    hipLaunchKernelGGL(count_pairs, dim3((N + 255) / 256), dim3(256), 0, stream,
                       nbr, kcnt, N);
    hipLaunchKernelGGL(scan_pairs, dim3(1), dim3(32), 0, stream,
                       kcnt, kbase, cursor, nseg, (int)PAIR_CAP);
    hipLaunchKernelGGL(fill_seg2k, dim3(SEGMAX / 256), dim3(256), 0, stream,
                       kbase, nseg, seg2k);
    hipLaunchKernelGGL(fill_pairs, dim3((N + 255) / 256), dim3(256), 0, stream,
                       nbr, kbase, kcnt, cursor, pairs, N);
    hipLaunchKernelGGL(zero_h, dim3(2048), dim3(256), 0, stream,
                       (float4*)h, (long)N * (C / 4));
    // conv1: scatter non-center into h, then fused center + BN + ReLU (in place)
    hipLaunchKernelGGL((scatter_k<1>), dim3(SEGMAX), dim3(512), 0, stream,
                       feats, w_conv1, pairs, kcnt, kbase, seg2k, nseg, gate, bidx, h);
    hipLaunchKernelGGL((center_epi<0>), dim3((N + 127) / 128), dim3(512), 0, stream,
                       feats, w_conv1, gate, bidx, bnscale, bnshift, h, h, N);
    // conv2: center + bias writes out, then scatter non-center on top
    hipLaunchKernelGGL((center_epi<1>), dim3((N + 127) / 128), dim3(512), 0, stream,
                       h, w_conv2, nullptr, nullptr, nullptr, b_conv2, nullptr, out, N);
    hipLaunchKernelGGL((scatter_k<0>), dim3(SEGMAX), dim3(512), 0, stream,
                       h, w_conv2, pairs, kcnt, kbase, seg2k, nseg, nullptr, nullptr, out);
  } else {
    // round-1 fallback path
    float* w1g = ws + 1024;
    float* h   = ws + 1024 + BB * KK * C * C;
    hipLaunchKernelGGL(init_ws, dim3(4), dim3(256), 0, stream, ws);
    hipLaunchKernelGGL(pool_kernel, dim3(1024), dim3(256), 0, stream,
                       (const float4*)feats, bidx, pooled, counts, N);
    hipLaunchKernelGGL(gate_kernel, dim3(1), dim3(256), 0, stream,
                       pooled, counts, w_fc1, b_fc1, w_fc2, b_fc2,
                       bn_gamma, bn_beta, bn_mean, bn_var, gate, bnscale, bnshift);
    hipLaunchKernelGGL(scale_w1, dim3(KK * BB), dim3(256), 0, stream,
                       w_conv1, gate, w1g);
    hipLaunchKernelGGL((spconv_kernel<0>), dim3((N + 3) / 4), dim3(256), 0, stream,
                       feats, nbr, bidx, w1g, bnscale, bnshift, h, N);
    hipLaunchKernelGGL((spconv_kernel<1>), dim3((N + 3) / 4), dim3(256), 0, stream,
                       h, nbr, bidx, w_conv2, nullptr, b_conv2, out, N);
  }
}

// Round 8
// 855.703 us; speedup vs baseline: 4.7189x; 1.1684x over previous
//
#include <hip/hip_runtime.h>

#define C  64
#define KK 27
#define BB 4

// ===================== fast-path ws layout (float offsets) =====================
//      0 : pooled[256]
//    256 : counts[4]
//    260 : gate[256]
//    516 : bnscale[64]
//    580 : bnshift[64]
//    698 : cursor[26] (int)       (per-j pair counts, j = k index skipping 13)
//  16384 : pairs[2*PAIR_CAP] (int)  (src,dst interleaved; region j at j*KSTRIDE)
//  16384+2*PAIR_CAP : h[N*C]
#define PAIR_CAP 1250000
#define KSTRIDE  40960          // pairs per offset region (multiple of 128)
#define SEGPK    (KSTRIDE / 128) // 320 segments per offset
#define NJ       26

__global__ __launch_bounds__(256) void init_ws(float* ws) {
  int t = blockIdx.x * 256 + threadIdx.x;
  if (t < 1024) ws[t] = 0.f;
}

// Grid-strided pooling: 16 threads per point row, float4 loads, shuffle+LDS reduce.
__global__ __launch_bounds__(256) void pool_kernel(
    const float4* __restrict__ x4, const int* __restrict__ bidx,
    float* __restrict__ pooled, float* __restrict__ counts, int N)
{
  int t = threadIdx.x;
  int g = t & 15;            // column group: floats [4g, 4g+4)
  int rowInBlk = t >> 4;     // 0..15
  int lane = t & 63, wv = t >> 6;
  float4 acc[BB];
#pragma unroll
  for (int b = 0; b < BB; ++b) acc[b] = make_float4(0.f, 0.f, 0.f, 0.f);
  int cnt[BB] = {0, 0, 0, 0};
  for (int n = blockIdx.x * 16 + rowInBlk; n < N; n += gridDim.x * 16) {
    int b = bidx[n];
    float4 v = x4[((size_t)n << 4) + g];
    if (b == 0)      { acc[0].x += v.x; acc[0].y += v.y; acc[0].z += v.z; acc[0].w += v.w; }
    else if (b == 1) { acc[1].x += v.x; acc[1].y += v.y; acc[1].z += v.z; acc[1].w += v.w; }
    else if (b == 2) { acc[2].x += v.x; acc[2].y += v.y; acc[2].z += v.z; acc[2].w += v.w; }
    else             { acc[3].x += v.x; acc[3].y += v.y; acc[3].z += v.z; acc[3].w += v.w; }
    if (g == 0) {
      if (b == 0) cnt[0]++; else if (b == 1) cnt[1]++;
      else if (b == 2) cnt[2]++; else cnt[3]++;
    }
  }
#pragma unroll
  for (int b = 0; b < BB; ++b) {
    acc[b].x += __shfl_xor(acc[b].x, 16); acc[b].y += __shfl_xor(acc[b].y, 16);
    acc[b].z += __shfl_xor(acc[b].z, 16); acc[b].w += __shfl_xor(acc[b].w, 16);
    acc[b].x += __shfl_xor(acc[b].x, 32); acc[b].y += __shfl_xor(acc[b].y, 32);
    acc[b].z += __shfl_xor(acc[b].z, 32); acc[b].w += __shfl_xor(acc[b].w, 32);
    cnt[b] += __shfl_xor(cnt[b], 16);
    cnt[b] += __shfl_xor(cnt[b], 32);
  }
  __shared__ float red[4][BB][16][4];
  __shared__ int cred[4][BB];
  if (lane < 16) {
#pragma unroll
    for (int b = 0; b < BB; ++b) {
      red[wv][b][lane][0] = acc[b].x; red[wv][b][lane][1] = acc[b].y;
      red[wv][b][lane][2] = acc[b].z; red[wv][b][lane][3] = acc[b].w;
    }
    if (lane == 0) {
#pragma unroll
      for (int b = 0; b < BB; ++b) cred[wv][b] = cnt[b];
    }
  }
  __syncthreads();
  {
    int b = t >> 6, rem = t & 63;   // 256 threads = 4b x 16g x 4comp
    int gg = rem >> 2, comp = rem & 3;
    float s = red[0][b][gg][comp] + red[1][b][gg][comp] +
              red[2][b][gg][comp] + red[3][b][gg][comp];
    if (s != 0.f) atomicAdd(&pooled[b * C + (gg << 2) + comp], s);
  }
  if (t < BB) {
    int s = cred[0][t] + cred[1][t] + cred[2][t] + cred[3][t];
    if (s) atomicAdd(&counts[t], (float)s);
  }
}

__global__ __launch_bounds__(256) void gate_kernel(
    const float* __restrict__ pooled, const float* __restrict__ counts,
    const float* __restrict__ w_fc1, const float* __restrict__ b_fc1,
    const float* __restrict__ w_fc2, const float* __restrict__ b_fc2,
    const float* __restrict__ bn_gamma, const float* __restrict__ bn_beta,
    const float* __restrict__ bn_mean, const float* __restrict__ bn_var,
    float* __restrict__ gate, float* __restrict__ bnscale, float* __restrict__ bnshift)
{
  __shared__ float mean[BB * C];
  __shared__ float hh[BB * 16];
  int t = threadIdx.x;
  { int b = t >> 6; mean[t] = pooled[t] / counts[b]; }
  __syncthreads();
  if (t < BB * 16) {
    int b = t >> 4, r = t & 15;
    float s = b_fc1[r];
    for (int c = 0; c < C; ++c) s += mean[b * C + c] * w_fc1[c * 16 + r];
    hh[t] = fmaxf(s, 0.f);
  }
  __syncthreads();
  {
    int b = t >> 6, c = t & 63;
    float s = b_fc2[c];
    for (int r = 0; r < 16; ++r) s += hh[b * 16 + r] * w_fc2[r * 64 + c];
    gate[t] = 1.f / (1.f + expf(-s));
  }
  if (t < C) {
    float sc = bn_gamma[t] * rsqrtf(bn_var[t] + 1e-5f);
    bnscale[t] = sc;
    bnshift[t] = bn_beta[t] - bn_mean[t] * sc;
  }
}

// ---------------- single-pass pair build (ballot, fixed per-j regions) ----------------
__global__ __launch_bounds__(256) void fill_pairs(
    const int* __restrict__ nbr, int* __restrict__ cursor,
    int* __restrict__ pairs, int N)
{
  __shared__ int wc[4][NJ];
  __shared__ int wb[4][NJ];
  int t = threadIdx.x, wv = t >> 6, lane = t & 63;
  int n = blockIdx.x * 256 + t;
  bool act = n < N;
  int v[NJ];
#pragma unroll
  for (int j = 0; j < NJ; ++j) {
    int k = j + (j >= 13);
    v[j] = act ? nbr[(size_t)k * N + n] : -1;
    unsigned long long m = __ballot(v[j] >= 0);
    if (lane == 0) wc[wv][j] = __popcll(m);
  }
  __syncthreads();
  if (t < NJ) {
    int c0 = wc[0][t], c1 = wc[1][t], c2 = wc[2][t], c3 = wc[3][t];
    int tot = c0 + c1 + c2 + c3;
    int b = tot ? atomicAdd(&cursor[t], tot) : 0;
    wb[0][t] = b; wb[1][t] = b + c0; wb[2][t] = b + c0 + c1; wb[3][t] = b + c0 + c1 + c2;
  }
  __syncthreads();
  unsigned long long lt = (1ull << lane) - 1ull;
#pragma unroll
  for (int j = 0; j < NJ; ++j) {
    bool val = v[j] >= 0;
    unsigned long long m = __ballot(val);
    if (!val) continue;
    int pos = wb[wv][j] + __popcll(m & lt);
    if (pos < KSTRIDE) {
      int slot = j * KSTRIDE + pos;
      pairs[slot * 2]     = v[j];   // src
      pairs[slot * 2 + 1] = n;      // dst
    }
  }
}

// ---------------- GEMM microkernel (512-thread): 128 rows x 64 cols ----------------
// 8 waves, wave wv owns rows [wv*16, wv*16+16); thread (pg,cg): rows {base, base+8},
// cols [cg*8, cg*8+8). Al stride 68 floats (4-bank row skew -> conflict-free b128).
__device__ __forceinline__ void gemm_micro2(const float* Al, const float* Wl,
                                            int rowBase, int coBase, float acc[2][8])
{
#pragma unroll
  for (int i = 0; i < 2; ++i)
#pragma unroll
    for (int j = 0; j < 8; ++j) acc[i][j] = 0.f;
#pragma unroll 4
  for (int ci = 0; ci < 64; ci += 4) {
    float av[2][4];
    *(float4*)av[0] = *(const float4*)&Al[(rowBase    ) * 68 + ci];
    *(float4*)av[1] = *(const float4*)&Al[(rowBase + 8) * 68 + ci];
#pragma unroll
    for (int q = 0; q < 4; ++q) {
      float w8[8];
      *(float4*)&w8[0] = *(const float4*)&Wl[(ci + q) * 64 + coBase];
      *(float4*)&w8[4] = *(const float4*)&Wl[(ci + q) * 64 + coBase + 4];
#pragma unroll
      for (int i = 0; i < 2; ++i)
#pragma unroll
        for (int j = 0; j < 8; ++j)
          acc[i][j] = fmaf(av[i][q], w8[j], acc[i][j]);
    }
  }
}

// ---------------- per-k gather-GEMM-scatter (coalesced atomics, 512 thr) ----------------
// MODE 1: conv1 scatter (A = feats * gate[bidx]), adds into h
// MODE 2: conv2 scatter (A = relu(h*bnA+bnB) on load), adds into out
template <int MODE>
__global__ __launch_bounds__(512) void scatter_k(
    const float* __restrict__ x, const float* __restrict__ Wfull,
    const int* __restrict__ pairs, const int* __restrict__ kcnt,
    const float* __restrict__ bnA, const float* __restrict__ bnB,
    const int* __restrict__ bidx, float* __restrict__ out)
{
  __shared__ float Wl[4096];
  __shared__ float Al[128 * 68];
  __shared__ int Sl[128], Dl[128];
  int j = blockIdx.x / SEGPK;
  int off = (blockIdx.x - j * SEGPK) << 7;
  int pCnt = min(128, kcnt[j] - off);
  if (pCnt <= 0) return;
  int k = j + (j >= 13);
  int t = threadIdx.x;
  int pBase = j * KSTRIDE + off;
  if (t < 128) {
    int s = -1, d = -1;
    if (t < pCnt) { s = pairs[(pBase + t) << 1]; d = pairs[((pBase + t) << 1) | 1]; }
    Sl[t] = s; Dl[t] = d;
  }
  const float* Ws = Wfull + ((size_t)k << 12);
  for (int i = t; i < 4096; i += 512) Wl[i] = Ws[i];
  __syncthreads();
  int rr = t >> 4, c4 = (t & 15) << 2;   // rr 0..31
  float4 a4, b4;
  if (MODE == 2) { a4 = *(const float4*)&bnA[c4]; b4 = *(const float4*)&bnB[c4]; }
  float4 tv[4];
#pragma unroll
  for (int it = 0; it < 4; ++it) {
    int r = (it << 5) + rr;
    float4 v = make_float4(0.f, 0.f, 0.f, 0.f);
    int src = Sl[r];
    if (src >= 0) {
      v = *(const float4*)(x + ((size_t)src << 6) + c4);
      if (MODE == 1) {
        const float* g = bnA + (bidx[src] << 6) + c4;   // bnA = gate base
        v.x *= g[0]; v.y *= g[1]; v.z *= g[2]; v.w *= g[3];
      } else {
        v.x = fmaxf(fmaf(v.x, a4.x, b4.x), 0.f);
        v.y = fmaxf(fmaf(v.y, a4.y, b4.y), 0.f);
        v.z = fmaxf(fmaf(v.z, a4.z, b4.z), 0.f);
        v.w = fmaxf(fmaf(v.w, a4.w, b4.w), 0.f);
      }
    }
    tv[it] = v;
  }
#pragma unroll
  for (int it = 0; it < 4; ++it) {
    int r = (it << 5) + rr;
    *(float4*)&Al[r * 68 + c4] = tv[it];
  }
  __syncthreads();
  int wv = t >> 6, lane = t & 63, pg = lane >> 3, cg = lane & 7;
  int rowBase = (wv << 4) + pg, coBase = cg << 3;
  float acc[2][8];
  gemm_micro2(Al, Wl, rowBase, coBase, acc);
  // round-trip result through LDS (reuse Al as O[128][68]) for coalesced atomics
  __syncthreads();
#pragma unroll
  for (int i = 0; i < 2; ++i) {
    int r = rowBase + (i << 3);
    *(float4*)&Al[r * 68 + coBase]     = *(const float4*)&acc[i][0];
    *(float4*)&Al[r * 68 + coBase + 4] = *(const float4*)&acc[i][4];
  }
  __syncthreads();
  // wave wv scatters rows [wv*16, wv*16+16): one atomic instr = 64 contiguous floats
  int w0 = wv << 4;
  for (int r2 = 0; r2 < 16; ++r2) {
    int r = w0 + r2;
    int d = Dl[r];
    if (d < 0) continue;
    float val = Al[r * 68 + lane];
    unsafeAtomicAdd(&out[((size_t)d << 6) + lane], val);
  }
}

// ---------------- dense center GEMM (512 thr) ----------------
// MODE 0: conv1 center — A = feats*gate, write raw acc to h (scatter adds after)
// MODE 1: conv2 center — A = relu(h*bnA+bnB) on load, write acc + bias to out
template <int MODE>
__global__ __launch_bounds__(512) void center_epi(
    const float* __restrict__ x, const float* __restrict__ Wfull,
    const float* __restrict__ gate, const int* __restrict__ bidx,
    const float* __restrict__ bnA, const float* __restrict__ bnB,
    const float* __restrict__ bias, float* __restrict__ out, int N)
{
  __shared__ float Wl[4096];
  __shared__ float Al[128 * 68];
  int t = threadIdx.x;
  int n0 = blockIdx.x << 7;
  int pCnt = min(128, N - n0);
  const float* Ws = Wfull + ((size_t)13 << 12);
  for (int i = t; i < 4096; i += 512) Wl[i] = Ws[i];
  int rr = t >> 4, c4 = (t & 15) << 2;
  float4 a4, b4;
  if (MODE == 1) { a4 = *(const float4*)&bnA[c4]; b4 = *(const float4*)&bnB[c4]; }
  float4 tv[4];
#pragma unroll
  for (int it = 0; it < 4; ++it) {
    int r = (it << 5) + rr;
    float4 v = make_float4(0.f, 0.f, 0.f, 0.f);
    if (r < pCnt) {
      int n = n0 + r;
      v = *(const float4*)(x + ((size_t)n << 6) + c4);
      if (MODE == 0) {
        const float* g = gate + (bidx[n] << 6) + c4;
        v.x *= g[0]; v.y *= g[1]; v.z *= g[2]; v.w *= g[3];
      } else {
        v.x = fmaxf(fmaf(v.x, a4.x, b4.x), 0.f);
        v.y = fmaxf(fmaf(v.y, a4.y, b4.y), 0.f);
        v.z = fmaxf(fmaf(v.z, a4.z, b4.z), 0.f);
        v.w = fmaxf(fmaf(v.w, a4.w, b4.w), 0.f);
      }
    }
    tv[it] = v;
  }
#pragma unroll
  for (int it = 0; it < 4; ++it) {
    int r = (it << 5) + rr;
    *(float4*)&Al[r * 68 + c4] = tv[it];
  }
  __syncthreads();
  int wv = t >> 6, lane = t & 63, pg = lane >> 3, cg = lane & 7;
  int rowBase = (wv << 4) + pg, coBase = cg << 3;
  float acc[2][8];
  gemm_micro2(Al, Wl, rowBase, coBase, acc);
  float4 bb0, bb1;
  if (MODE == 1) { bb0 = *(const float4*)&bias[coBase]; bb1 = *(const float4*)&bias[coBase + 4]; }
#pragma unroll
  for (int i = 0; i < 2; ++i) {
    int r = rowBase + (i << 3);
    if (r < pCnt) {
      size_t o = (((size_t)(n0 + r)) << 6) + coBase;
      float4 r0, r1;
      if (MODE == 0) {
        r0 = make_float4(acc[i][0], acc[i][1], acc[i][2], acc[i][3]);
        r1 = make_float4(acc[i][4], acc[i][5], acc[i][6], acc[i][7]);
      } else {
        r0 = make_float4(acc[i][0] + bb0.x, acc[i][1] + bb0.y,
                         acc[i][2] + bb0.z, acc[i][3] + bb0.w);
        r1 = make_float4(acc[i][4] + bb1.x, acc[i][5] + bb1.y,
                         acc[i][6] + bb1.z, acc[i][7] + bb1.w);
      }
      *(float4*)&out[o]     = r0;
      *(float4*)&out[o + 4] = r1;
    }
  }
}

// ---------------- round-1 fallback (small ws) ----------------
__global__ __launch_bounds__(256) void scale_w1(
    const float* __restrict__ w1, const float* __restrict__ gate,
    float* __restrict__ w1g)
{
  int b = blockIdx.x & 3, k = blockIdx.x >> 2;
  const float* src = w1 + ((size_t)k << 12);
  float* dst = w1g + (((size_t)(b * KK + k)) << 12);
  const float* g = gate + (b << 6);
  for (int it = 0; it < 16; ++it) {
    int pos = it * 256 + threadIdx.x;
    int ci = pos >> 6;
    dst[pos] = g[ci] * src[pos];
  }
}

template <int MODE>
__global__ __launch_bounds__(256) void spconv_kernel(
    const float* __restrict__ x, const int* __restrict__ nbr,
    const int* __restrict__ bidx, const float* __restrict__ W,
    const float* __restrict__ ep_a, const float* __restrict__ ep_b,
    float* __restrict__ out, int N)
{
  int wid = (int)((blockIdx.x * 256u + threadIdx.x) >> 6);
  if (wid >= N) return;
  int lane = threadIdx.x & 63;
  int n = __builtin_amdgcn_readfirstlane(wid);
  const float* Wb = W;
  if (MODE == 0) {
    int b = __builtin_amdgcn_readfirstlane(bidx[n]);
    Wb += (size_t)b * (KK * C * C);
  }
  float acc = 0.f;
#pragma unroll 1
  for (int k = 0; k < KK; ++k) {
    int idx = __builtin_amdgcn_readfirstlane(nbr[(size_t)k * N + n]);
    if (idx < 0) continue;
    const float* xr = x + ((size_t)idx << 6);
    const float* wr = Wb + (k << 12) + lane;
#pragma unroll
    for (int ci = 0; ci < C; ++ci) acc = fmaf(xr[ci], wr[ci << 6], acc);
  }
  float r;
  if (MODE == 0) r = fmaxf(fmaf(acc, ep_a[lane], ep_b[lane]), 0.f);
  else           r = acc + ep_b[lane];
  out[((size_t)n << 6) + lane] = r;
}

extern "C" void kernel_launch(void* const* d_in, const int* in_sizes, int n_in,
                              void* d_out, int out_size, void* d_ws, size_t ws_size,
                              hipStream_t stream) {
  const float* feats   = (const float*)d_in[0];
  const int*   nbr     = (const int*)  d_in[1];
  const int*   bidx    = (const int*)  d_in[2];
  const float* w_fc1   = (const float*)d_in[3];
  const float* b_fc1   = (const float*)d_in[4];
  const float* w_fc2   = (const float*)d_in[5];
  const float* b_fc2   = (const float*)d_in[6];
  const float* w_conv1 = (const float*)d_in[7];
  const float* bn_gamma= (const float*)d_in[8];
  const float* bn_beta = (const float*)d_in[9];
  const float* bn_mean = (const float*)d_in[10];
  const float* bn_var  = (const float*)d_in[11];
  const float* w_conv2 = (const float*)d_in[12];
  const float* b_conv2 = (const float*)d_in[13];

  int N = in_sizes[0] / C;
  float* ws      = (float*)d_ws;
  float* pooled  = ws;
  float* counts  = ws + 256;
  float* gate    = ws + 260;
  float* bnscale = ws + 516;
  float* bnshift = ws + 580;
  float* out     = (float*)d_out;

  size_t need = ((size_t)16384 + 2ull * PAIR_CAP + (size_t)N * C) * 4ull;

  if (ws_size >= need) {
    int* cursor = (int*)(ws + 698);
    int* pairs  = (int*)(ws + 16384);
    float* h    = ws + 16384 + 2ull * PAIR_CAP;

    hipLaunchKernelGGL(init_ws, dim3(4), dim3(256), 0, stream, ws);
    hipLaunchKernelGGL(pool_kernel, dim3(1024), dim3(256), 0, stream,
                       (const float4*)feats, bidx, pooled, counts, N);
    hipLaunchKernelGGL(gate_kernel, dim3(1), dim3(256), 0, stream,
                       pooled, counts, w_fc1, b_fc1, w_fc2, b_fc2,
                       bn_gamma, bn_beta, bn_mean, bn_var, gate, bnscale, bnshift);
    hipLaunchKernelGGL(fill_pairs, dim3((N + 255) / 256), dim3(256), 0, stream,
                       nbr, cursor, pairs, N);
    // conv1: center writes h (raw), then scatter adds (gated gathers from feats)
    hipLaunchKernelGGL((center_epi<0>), dim3((N + 127) / 128), dim3(512), 0, stream,
                       feats, w_conv1, gate, bidx, nullptr, nullptr, nullptr, h, N);
    hipLaunchKernelGGL((scatter_k<1>), dim3(NJ * SEGPK), dim3(512), 0, stream,
                       feats, w_conv1, pairs, cursor, gate, nullptr, bidx, h);
    // conv2: BN+ReLU folded into A-loads; center writes out (+bias), scatter adds
    hipLaunchKernelGGL((center_epi<1>), dim3((N + 127) / 128), dim3(512), 0, stream,
                       h, w_conv2, nullptr, nullptr, bnscale, bnshift, b_conv2, out, N);
    hipLaunchKernelGGL((scatter_k<2>), dim3(NJ * SEGPK), dim3(512), 0, stream,
                       h, w_conv2, pairs, cursor, bnscale, bnshift, nullptr, out);
  } else {
    // round-1 fallback path
    float* w1g = ws + 1024;
    float* h   = ws + 1024 + BB * KK * C * C;
    hipLaunchKernelGGL(init_ws, dim3(4), dim3(256), 0, stream, ws);
    hipLaunchKernelGGL(pool_kernel, dim3(1024), dim3(256), 0, stream,
                       (const float4*)feats, bidx, pooled, counts, N);
    hipLaunchKernelGGL(gate_kernel, dim3(1), dim3(256), 0, stream,
                       pooled, counts, w_fc1, b_fc1, w_fc2, b_fc2,
                       bn_gamma, bn_beta, bn_mean, bn_var, gate, bnscale, bnshift);
    hipLaunchKernelGGL(scale_w1, dim3(KK * BB), dim3(256), 0, stream,
                       w_conv1, gate, w1g);
    hipLaunchKernelGGL((spconv_kernel<0>), dim3((N + 3) / 4), dim3(256), 0, stream,
                       feats, nbr, bidx, w1g, bnscale, bnshift, h, N);
    hipLaunchKernelGGL((spconv_kernel<1>), dim3((N + 3) / 4), dim3(256), 0, stream,
                       h, nbr, bidx, w_conv2, nullptr, b_conv2, out, N);
  }
}

// Round 9
// 721.057 us; speedup vs baseline: 5.6001x; 1.1867x over previous
//
#include <hip/hip_runtime.h>

#define C  64
#define KK 27
#define BB 4

typedef _Float16 h4 __attribute__((ext_vector_type(4)));
typedef _Float16 h8 __attribute__((ext_vector_type(8)));
typedef float    f4 __attribute__((ext_vector_type(4)));

// ===================== fast-path ws layout (float offsets) =====================
//      0 : pooled[256]
//    256 : counts[4]
//    260 : gate[256]
//    516 : bnscale[64]
//    580 : bnshift[64]
//    698 : cursor[26] (int)
//   1024 : Wf1[27*4096 halfs]  (55296 floats)
//  56320 : Wf2[27*4096 halfs]  (55296 floats)
// 114688 : pairs[NJ*KSTRIDE*2] (int)
// 114688+2129920 : h[N*C]
#define KSTRIDE  40960           // pairs per offset region (multiple of 128)
#define SEGPK    (KSTRIDE / 128) // 320 segments per offset
#define NJ       26
#define PAIRS_OFF 114688
#define H_OFF    (PAIRS_OFF + 2 * NJ * KSTRIDE)

__global__ __launch_bounds__(256) void init_ws(float* ws) {
  int t = blockIdx.x * 256 + threadIdx.x;
  if (t < 1024) ws[t] = 0.f;
}

// Grid-strided pooling: 16 threads per point row, float4 loads, shuffle+LDS reduce.
__global__ __launch_bounds__(256) void pool_kernel(
    const float4* __restrict__ x4, const int* __restrict__ bidx,
    float* __restrict__ pooled, float* __restrict__ counts, int N)
{
  int t = threadIdx.x;
  int g = t & 15;
  int rowInBlk = t >> 4;
  int lane = t & 63, wv = t >> 6;
  float4 acc[BB];
#pragma unroll
  for (int b = 0; b < BB; ++b) acc[b] = make_float4(0.f, 0.f, 0.f, 0.f);
  int cnt[BB] = {0, 0, 0, 0};
  for (int n = blockIdx.x * 16 + rowInBlk; n < N; n += gridDim.x * 16) {
    int b = bidx[n];
    float4 v = x4[((size_t)n << 4) + g];
    if (b == 0)      { acc[0].x += v.x; acc[0].y += v.y; acc[0].z += v.z; acc[0].w += v.w; }
    else if (b == 1) { acc[1].x += v.x; acc[1].y += v.y; acc[1].z += v.z; acc[1].w += v.w; }
    else if (b == 2) { acc[2].x += v.x; acc[2].y += v.y; acc[2].z += v.z; acc[2].w += v.w; }
    else             { acc[3].x += v.x; acc[3].y += v.y; acc[3].z += v.z; acc[3].w += v.w; }
    if (g == 0) {
      if (b == 0) cnt[0]++; else if (b == 1) cnt[1]++;
      else if (b == 2) cnt[2]++; else cnt[3]++;
    }
  }
#pragma unroll
  for (int b = 0; b < BB; ++b) {
    acc[b].x += __shfl_xor(acc[b].x, 16); acc[b].y += __shfl_xor(acc[b].y, 16);
    acc[b].z += __shfl_xor(acc[b].z, 16); acc[b].w += __shfl_xor(acc[b].w, 16);
    acc[b].x += __shfl_xor(acc[b].x, 32); acc[b].y += __shfl_xor(acc[b].y, 32);
    acc[b].z += __shfl_xor(acc[b].z, 32); acc[b].w += __shfl_xor(acc[b].w, 32);
    cnt[b] += __shfl_xor(cnt[b], 16);
    cnt[b] += __shfl_xor(cnt[b], 32);
  }
  __shared__ float red[4][BB][16][4];
  __shared__ int cred[4][BB];
  if (lane < 16) {
#pragma unroll
    for (int b = 0; b < BB; ++b) {
      red[wv][b][lane][0] = acc[b].x; red[wv][b][lane][1] = acc[b].y;
      red[wv][b][lane][2] = acc[b].z; red[wv][b][lane][3] = acc[b].w;
    }
    if (lane == 0) {
#pragma unroll
      for (int b = 0; b < BB; ++b) cred[wv][b] = cnt[b];
    }
  }
  __syncthreads();
  {
    int b = t >> 6, rem = t & 63;
    int gg = rem >> 2, comp = rem & 3;
    float s = red[0][b][gg][comp] + red[1][b][gg][comp] +
              red[2][b][gg][comp] + red[3][b][gg][comp];
    if (s != 0.f) atomicAdd(&pooled[b * C + (gg << 2) + comp], s);
  }
  if (t < BB) {
    int s = cred[0][t] + cred[1][t] + cred[2][t] + cred[3][t];
    if (s) atomicAdd(&counts[t], (float)s);
  }
}

__global__ __launch_bounds__(256) void gate_kernel(
    const float* __restrict__ pooled, const float* __restrict__ counts,
    const float* __restrict__ w_fc1, const float* __restrict__ b_fc1,
    const float* __restrict__ w_fc2, const float* __restrict__ b_fc2,
    const float* __restrict__ bn_gamma, const float* __restrict__ bn_beta,
    const float* __restrict__ bn_mean, const float* __restrict__ bn_var,
    float* __restrict__ gate, float* __restrict__ bnscale, float* __restrict__ bnshift)
{
  __shared__ float mean[BB * C];
  __shared__ float hh[BB * 16];
  int t = threadIdx.x;
  { int b = t >> 6; mean[t] = pooled[t] / counts[b]; }
  __syncthreads();
  if (t < BB * 16) {
    int b = t >> 4, r = t & 15;
    float s = b_fc1[r];
    for (int c = 0; c < C; ++c) s += mean[b * C + c] * w_fc1[c * 16 + r];
    hh[t] = fmaxf(s, 0.f);
  }
  __syncthreads();
  {
    int b = t >> 6, c = t & 63;
    float s = b_fc2[c];
    for (int r = 0; r < 16; ++r) s += hh[b * 16 + r] * w_fc2[r * 64 + c];
    gate[t] = 1.f / (1.f + expf(-s));
  }
  if (t < C) {
    float sc = bn_gamma[t] * rsqrtf(bn_var[t] + 1e-5f);
    bnscale[t] = sc;
    bnshift[t] = bn_beta[t] - bn_mean[t] * sc;
  }
}

// ---------------- pack W into f16 fragment-major layout ----------------
// Fragment (kt,ct) of W[k]: B[k'][col], k' = ci&31, col = co&15, ct = co>>4, kt = ci>>5.
// lane = ((ci>>3)&3)*16 + (co&15), elem i = ci&7.
// halfs addr = k*4096 + (kt*4+ct)*512 + lane*8 + i
__global__ __launch_bounds__(256) void w_pack(
    const float* __restrict__ W1, const float* __restrict__ W2,
    _Float16* __restrict__ Wf1, _Float16* __restrict__ Wf2)
{
  int kk = blockIdx.x;
  const float* src = (kk < KK) ? (W1 + ((size_t)kk << 12)) : (W2 + ((size_t)(kk - KK) << 12));
  _Float16* dst = (kk < KK) ? (Wf1 + ((size_t)kk << 12)) : (Wf2 + ((size_t)(kk - KK) << 12));
  int t = threadIdx.x;
  for (int e = 0; e < 16; ++e) {
    int idx = e * 256 + t;
    int ci = idx >> 6, co = idx & 63;
    int kt = ci >> 5, i = ci & 7, lh = (ci >> 3) & 3, ct = co >> 4, col = co & 15;
    int lane = lh * 16 + col;
    dst[((kt * 4 + ct) * 64 + lane) * 8 + i] = (_Float16)src[idx];
  }
}

// ---------------- single-pass pair build (ballot, fixed per-j regions) ----------------
__global__ __launch_bounds__(256) void fill_pairs(
    const int* __restrict__ nbr, int* __restrict__ cursor,
    int* __restrict__ pairs, int N)
{
  __shared__ int wc[4][NJ];
  __shared__ int wb[4][NJ];
  int t = threadIdx.x, wv = t >> 6, lane = t & 63;
  int n = blockIdx.x * 256 + t;
  bool act = n < N;
  int v[NJ];
#pragma unroll
  for (int j = 0; j < NJ; ++j) {
    int k = j + (j >= 13);
    v[j] = act ? nbr[(size_t)k * N + n] : -1;
    unsigned long long m = __ballot(v[j] >= 0);
    if (lane == 0) wc[wv][j] = __popcll(m);
  }
  __syncthreads();
  if (t < NJ) {
    int c0 = wc[0][t], c1 = wc[1][t], c2 = wc[2][t], c3 = wc[3][t];
    int tot = c0 + c1 + c2 + c3;
    int b = tot ? atomicAdd(&cursor[t], tot) : 0;
    wb[0][t] = b; wb[1][t] = b + c0; wb[2][t] = b + c0 + c1; wb[3][t] = b + c0 + c1 + c2;
  }
  __syncthreads();
  unsigned long long lt = (1ull << lane) - 1ull;
#pragma unroll
  for (int j = 0; j < NJ; ++j) {
    bool val = v[j] >= 0;
    unsigned long long m = __ballot(val);
    if (!val) continue;
    int pos = wb[wv][j] + __popcll(m & lt);
    if (pos < KSTRIDE) {
      int slot = j * KSTRIDE + pos;
      pairs[slot * 2]     = v[j];   // src
      pairs[slot * 2 + 1] = n;      // dst
    }
  }
}

// ---------------- MFMA GEMM core (per wave: 16 rows x 64 cols x K=64) ----------------
// A from LDS f16 [128][72]; B frags from global Wf (fragment-major); acc fp32.
__device__ __forceinline__ void mfma_tile(const _Float16* Af, const h8* Wb,
                                          int wv, int lane, f4 acc[4])
{
  int arow = (wv << 4) + (lane & 15);
  int koff = (lane >> 4) << 3;
  h8 a0 = *(const h8*)&Af[arow * 72 + koff];
  h8 a1 = *(const h8*)&Af[arow * 72 + 32 + koff];
#pragma unroll
  for (int ct = 0; ct < 4; ++ct) {
    h8 b0 = Wb[ct * 64 + lane];
    h8 b1 = Wb[(4 + ct) * 64 + lane];
    f4 c = {0.f, 0.f, 0.f, 0.f};
    c = __builtin_amdgcn_mfma_f32_16x16x32_f16(a0, b0, c, 0, 0, 0);
    c = __builtin_amdgcn_mfma_f32_16x16x32_f16(a1, b1, c, 0, 0, 0);
    acc[ct] = c;
  }
}

// ---------------- per-k gather-MFMA-scatter (coalesced atomics, 512 thr) ----------------
// MODE 1: conv1 scatter (A = feats * gate[bidx]), adds into h
// MODE 2: conv2 scatter (A = relu(h*bnA+bnB) on load), adds into out
template <int MODE>
__global__ __launch_bounds__(512) void scatter_k(
    const float* __restrict__ x, const _Float16* __restrict__ Wf,
    const int* __restrict__ pairs, const int* __restrict__ kcnt,
    const float* __restrict__ bnA, const float* __restrict__ bnB,
    const int* __restrict__ bidx, float* __restrict__ out)
{
  __shared__ int Sl[128], Dl[128];
  __shared__ __align__(16) char uni[128 * 68 * 4];   // union: Af f16 [128][72] | Ol f32 [128][68]
  _Float16* Af = (_Float16*)uni;
  float* Ol = (float*)uni;
  int j = blockIdx.x / SEGPK;
  int off = (blockIdx.x - j * SEGPK) << 7;
  int pCnt = min(128, kcnt[j] - off);
  if (pCnt <= 0) return;
  int k = j + (j >= 13);
  int t = threadIdx.x;
  int pBase = j * KSTRIDE + off;
  if (t < 128) {
    int s = -1, d = -1;
    if (t < pCnt) { s = pairs[(pBase + t) << 1]; d = pairs[((pBase + t) << 1) | 1]; }
    Sl[t] = s; Dl[t] = d;
  }
  __syncthreads();
  int rr = t >> 4, c4 = (t & 15) << 2;   // rr 0..31
  float4 a4, b4;
  if (MODE == 2) { a4 = *(const float4*)&bnA[c4]; b4 = *(const float4*)&bnB[c4]; }
  float4 tv[4];
#pragma unroll
  for (int it = 0; it < 4; ++it) {
    int r = (it << 5) + rr;
    float4 v = make_float4(0.f, 0.f, 0.f, 0.f);
    int src = Sl[r];
    if (src >= 0) {
      v = *(const float4*)(x + ((size_t)src << 6) + c4);
      if (MODE == 1) {
        const float* g = bnA + (bidx[src] << 6) + c4;   // bnA = gate base
        v.x *= g[0]; v.y *= g[1]; v.z *= g[2]; v.w *= g[3];
      } else {
        v.x = fmaxf(fmaf(v.x, a4.x, b4.x), 0.f);
        v.y = fmaxf(fmaf(v.y, a4.y, b4.y), 0.f);
        v.z = fmaxf(fmaf(v.z, a4.z, b4.z), 0.f);
        v.w = fmaxf(fmaf(v.w, a4.w, b4.w), 0.f);
      }
    }
    tv[it] = v;
  }
#pragma unroll
  for (int it = 0; it < 4; ++it) {
    int r = (it << 5) + rr;
    h4 hv = { (_Float16)tv[it].x, (_Float16)tv[it].y, (_Float16)tv[it].z, (_Float16)tv[it].w };
    *(h4*)&Af[r * 72 + c4] = hv;
  }
  __syncthreads();
  int wv = t >> 6, lane = t & 63;
  f4 acc[4];
  mfma_tile(Af, (const h8*)(Wf + ((size_t)k << 12)), wv, lane, acc);
  __syncthreads();   // done reading Af; reuse as Ol
  int orow0 = (wv << 4) + ((lane >> 4) << 2);
  int ocol = lane & 15;
#pragma unroll
  for (int ct = 0; ct < 4; ++ct)
#pragma unroll
    for (int rg = 0; rg < 4; ++rg)
      Ol[(orow0 + rg) * 68 + ct * 16 + ocol] = acc[ct][rg];
  __syncthreads();
  // wave wv scatters rows [wv*16, wv*16+16): one atomic instr = 64 contiguous floats
  int w0 = wv << 4;
  for (int r2 = 0; r2 < 16; ++r2) {
    int r = w0 + r2;
    int d = Dl[r];
    if (d < 0) continue;
    float val = Ol[r * 68 + lane];
    unsafeAtomicAdd(&out[((size_t)d << 6) + lane], val);
  }
}

// ---------------- dense center MFMA GEMM (512 thr, direct stores) ----------------
// MODE 0: conv1 center — A = feats*gate, write raw acc to h (scatter adds after)
// MODE 1: conv2 center — A = relu(h*bnA+bnB) on load, write acc + bias to out
template <int MODE>
__global__ __launch_bounds__(512) void center_epi(
    const float* __restrict__ x, const _Float16* __restrict__ Wf,
    const float* __restrict__ gate, const int* __restrict__ bidx,
    const float* __restrict__ bnA, const float* __restrict__ bnB,
    const float* __restrict__ bias, float* __restrict__ out, int N)
{
  __shared__ __align__(16) char uni[128 * 72 * 2];
  _Float16* Af = (_Float16*)uni;
  int t = threadIdx.x;
  int n0 = blockIdx.x << 7;
  int pCnt = min(128, N - n0);
  int rr = t >> 4, c4 = (t & 15) << 2;
  float4 a4, b4;
  if (MODE == 1) { a4 = *(const float4*)&bnA[c4]; b4 = *(const float4*)&bnB[c4]; }
  float4 tv[4];
#pragma unroll
  for (int it = 0; it < 4; ++it) {
    int r = (it << 5) + rr;
    float4 v = make_float4(0.f, 0.f, 0.f, 0.f);
    if (r < pCnt) {
      int n = n0 + r;
      v = *(const float4*)(x + ((size_t)n << 6) + c4);
      if (MODE == 0) {
        const float* g = gate + (bidx[n] << 6) + c4;
        v.x *= g[0]; v.y *= g[1]; v.z *= g[2]; v.w *= g[3];
      } else {
        v.x = fmaxf(fmaf(v.x, a4.x, b4.x), 0.f);
        v.y = fmaxf(fmaf(v.y, a4.y, b4.y), 0.f);
        v.z = fmaxf(fmaf(v.z, a4.z, b4.z), 0.f);
        v.w = fmaxf(fmaf(v.w, a4.w, b4.w), 0.f);
      }
    }
    tv[it] = v;
  }
#pragma unroll
  for (int it = 0; it < 4; ++it) {
    int r = (it << 5) + rr;
    h4 hv = { (_Float16)tv[it].x, (_Float16)tv[it].y, (_Float16)tv[it].z, (_Float16)tv[it].w };
    *(h4*)&Af[r * 72 + c4] = hv;
  }
  __syncthreads();
  int wv = t >> 6, lane = t & 63;
  f4 acc[4];
  mfma_tile(Af, (const h8*)(Wf + ((size_t)13 << 12)), wv, lane, acc);
  // direct global stores from fragments: row = wv*16 + (lane>>4)*4 + rg, col = ct*16 + (lane&15)
  int orow0 = (wv << 4) + ((lane >> 4) << 2);
  int ocol = lane & 15;
#pragma unroll
  for (int ct = 0; ct < 4; ++ct) {
    float bv = (MODE == 1) ? bias[ct * 16 + ocol] : 0.f;
#pragma unroll
    for (int rg = 0; rg < 4; ++rg) {
      int r = orow0 + rg;
      if (r < pCnt)
        out[(((size_t)(n0 + r)) << 6) + ct * 16 + ocol] = acc[ct][rg] + bv;
    }
  }
}

// ---------------- round-1 fallback (small ws) ----------------
__global__ __launch_bounds__(256) void scale_w1(
    const float* __restrict__ w1, const float* __restrict__ gate,
    float* __restrict__ w1g)
{
  int b = blockIdx.x & 3, k = blockIdx.x >> 2;
  const float* src = w1 + ((size_t)k << 12);
  float* dst = w1g + (((size_t)(b * KK + k)) << 12);
  const float* g = gate + (b << 6);
  for (int it = 0; it < 16; ++it) {
    int pos = it * 256 + threadIdx.x;
    int ci = pos >> 6;
    dst[pos] = g[ci] * src[pos];
  }
}

template <int MODE>
__global__ __launch_bounds__(256) void spconv_kernel(
    const float* __restrict__ x, const int* __restrict__ nbr,
    const int* __restrict__ bidx, const float* __restrict__ W,
    const float* __restrict__ ep_a, const float* __restrict__ ep_b,
    float* __restrict__ out, int N)
{
  int wid = (int)((blockIdx.x * 256u + threadIdx.x) >> 6);
  if (wid >= N) return;
  int lane = threadIdx.x & 63;
  int n = __builtin_amdgcn_readfirstlane(wid);
  const float* Wb = W;
  if (MODE == 0) {
    int b = __builtin_amdgcn_readfirstlane(bidx[n]);
    Wb += (size_t)b * (KK * C * C);
  }
  float acc = 0.f;
#pragma unroll 1
  for (int k = 0; k < KK; ++k) {
    int idx = __builtin_amdgcn_readfirstlane(nbr[(size_t)k * N + n]);
    if (idx < 0) continue;
    const float* xr = x + ((size_t)idx << 6);
    const float* wr = Wb + (k << 12) + lane;
#pragma unroll
    for (int ci = 0; ci < C; ++ci) acc = fmaf(xr[ci], wr[ci << 6], acc);
  }
  float r;
  if (MODE == 0) r = fmaxf(fmaf(acc, ep_a[lane], ep_b[lane]), 0.f);
  else           r = acc + ep_b[lane];
  out[((size_t)n << 6) + lane] = r;
}

extern "C" void kernel_launch(void* const* d_in, const int* in_sizes, int n_in,
                              void* d_out, int out_size, void* d_ws, size_t ws_size,
                              hipStream_t stream) {
  const float* feats   = (const float*)d_in[0];
  const int*   nbr     = (const int*)  d_in[1];
  const int*   bidx    = (const int*)  d_in[2];
  const float* w_fc1   = (const float*)d_in[3];
  const float* b_fc1   = (const float*)d_in[4];
  const float* w_fc2   = (const float*)d_in[5];
  const float* b_fc2   = (const float*)d_in[6];
  const float* w_conv1 = (const float*)d_in[7];
  const float* bn_gamma= (const float*)d_in[8];
  const float* bn_beta = (const float*)d_in[9];
  const float* bn_mean = (const float*)d_in[10];
  const float* bn_var  = (const float*)d_in[11];
  const float* w_conv2 = (const float*)d_in[12];
  const float* b_conv2 = (const float*)d_in[13];

  int N = in_sizes[0] / C;
  float* ws      = (float*)d_ws;
  float* pooled  = ws;
  float* counts  = ws + 256;
  float* gate    = ws + 260;
  float* bnscale = ws + 516;
  float* bnshift = ws + 580;
  float* out     = (float*)d_out;

  size_t need = ((size_t)H_OFF + (size_t)N * C) * 4ull;

  if (ws_size >= need) {
    int* cursor = (int*)(ws + 698);
    _Float16* Wf1 = (_Float16*)(ws + 1024);
    _Float16* Wf2 = (_Float16*)(ws + 56320);
    int* pairs  = (int*)(ws + PAIRS_OFF);
    float* h    = ws + H_OFF;

    hipLaunchKernelGGL(init_ws, dim3(4), dim3(256), 0, stream, ws);
    hipLaunchKernelGGL(pool_kernel, dim3(1024), dim3(256), 0, stream,
                       (const float4*)feats, bidx, pooled, counts, N);
    hipLaunchKernelGGL(gate_kernel, dim3(1), dim3(256), 0, stream,
                       pooled, counts, w_fc1, b_fc1, w_fc2, b_fc2,
                       bn_gamma, bn_beta, bn_mean, bn_var, gate, bnscale, bnshift);
    hipLaunchKernelGGL(w_pack, dim3(2 * KK), dim3(256), 0, stream,
                       w_conv1, w_conv2, Wf1, Wf2);
    hipLaunchKernelGGL(fill_pairs, dim3((N + 255) / 256), dim3(256), 0, stream,
                       nbr, cursor, pairs, N);
    // conv1: center writes h (raw), then scatter adds (gated gathers from feats)
    hipLaunchKernelGGL((center_epi<0>), dim3((N + 127) / 128), dim3(512), 0, stream,
                       feats, Wf1, gate, bidx, nullptr, nullptr, nullptr, h, N);
    hipLaunchKernelGGL((scatter_k<1>), dim3(NJ * SEGPK), dim3(512), 0, stream,
                       feats, Wf1, pairs, cursor, gate, nullptr, bidx, h);
    // conv2: BN+ReLU folded into A-loads; center writes out (+bias), scatter adds
    hipLaunchKernelGGL((center_epi<1>), dim3((N + 127) / 128), dim3(512), 0, stream,
                       h, Wf2, nullptr, nullptr, bnscale, bnshift, b_conv2, out, N);
    hipLaunchKernelGGL((scatter_k<2>), dim3(NJ * SEGPK), dim3(512), 0, stream,
                       h, Wf2, pairs, cursor, bnscale, bnshift, nullptr, out);
  } else {
    // round-1 fallback path
    float* w1g = ws + 1024;
    float* h   = ws + 1024 + BB * KK * C * C;
    hipLaunchKernelGGL(init_ws, dim3(4), dim3(256), 0, stream, ws);
    hipLaunchKernelGGL(pool_kernel, dim3(1024), dim3(256), 0, stream,
                       (const float4*)feats, bidx, pooled, counts, N);
    hipLaunchKernelGGL(gate_kernel, dim3(1), dim3(256), 0, stream,
                       pooled, counts, w_fc1, b_fc1, w_fc2, b_fc2,
                       bn_gamma, bn_beta, bn_mean, bn_var, gate, bnscale, bnshift);
    hipLaunchKernelGGL(scale_w1, dim3(KK * BB), dim3(256), 0, stream,
                       w_conv1, gate, w1g);
    hipLaunchKernelGGL((spconv_kernel<0>), dim3((N + 3) / 4), dim3(256), 0, stream,
                       feats, nbr, bidx, w1g, bnscale, bnshift, h, N);
    hipLaunchKernelGGL((spconv_kernel<1>), dim3((N + 3) / 4), dim3(256), 0, stream,
                       h, nbr, bidx, w_conv2, nullptr, b_conv2, out, N);
  }
}